// Round 1
// 224.864 us; speedup vs baseline: 1.0748x; 1.0748x over previous
//
#include <hip/hip_runtime.h>
#include <stdint.h>

// Problem constants
#define BB 64
#define VV 2000
#define DD 16
#define CI 64
#define CO 64

// ---- ws layout ----
// dword offsets (fp32 region)
#define WS_INV_DW   0
#define WS_GRAM_DW  8
#define WS_Z_DW     1024                    // float2[16][4096]
#define WS_BIAS_DW  132096                  // fp32 [2000][128]  (idx = 2*o+half)
// byte offsets (bf16 regions), all 16B-aligned
#define WS_NE_B     1552384UL               // bf16 [2048][64]  (hi/lo split ne)
#define WS_RHS_B    1814528UL               // bf16 [16384][64] compact RHS
#define WS_U_B      4960256UL               // bf16 [2000][3][64][64] compact U
#define WS_W_B      54112256UL              // bf16 [2000][4][64][64] compact W
// ZP (k_z partials) aliases the W region: consumed by k_zred BEFORE k_wgemm.
#define WS_ZP_DW    (WS_W_B / 4)

typedef __attribute__((ext_vector_type(8))) short short8;
typedef __attribute__((ext_vector_type(4))) float f32x4;

__device__ __forceinline__ uint32_t f2bf(float f) {
  uint32_t u = __float_as_uint(f);
  return (u + 0x7FFFu + ((u >> 16) & 1u)) >> 16;   // RNE
}

// ---------------------------------------------------------------------------
// K0: zero INV+GRAM (dwords [0,1024))
__global__ void k_zero(float* __restrict__ ws) {
  reinterpret_cast<float4*>(ws)[threadIdx.x] = make_float4(0.f, 0.f, 0.f, 0.f);
}

// K1: NE[u][col] bf16, col = h*32 + d*2 + p; h=0: bf16(ne), h=1: bf16(ne - hi)
__global__ void k_ne(const float* __restrict__ ne_re, const float* __restrict__ ne_im,
                     float* __restrict__ ws) {
  int gid = blockIdx.x * 256 + threadIdx.x;   // 512 blocks -> 131072
  int u = gid >> 6, col = gid & 63;
  int h = col >> 5, kk = col & 31, d = kk >> 1, p = kk & 1;
  float v = 0.f;
  if (u < VV) v = p ? ne_im[u*DD + d] : ne_re[u*DD + d];
  uint32_t hi = f2bf(v);
  uint32_t ov = h ? f2bf(v - __uint_as_float(hi << 16)) : hi;
  ((uint16_t*)((char*)ws + WS_NE_B))[gid] = (uint16_t)ov;
}

// K2: compact RHS[n'][k], n' = c*4096 + o*64 + s*8 + e (granule-swizzle baked:
// s = (ig ^ (o&7))&7). Components c: 0=Ar-maker, 1=Ai, 2=Br, 3=Bi.
// cols k = h*32 + d*2 + p: p0 multiplies nr, p1 multiplies ni.
__global__ void k_rhs(const float* __restrict__ w_re, const float* __restrict__ w_im,
                      float* __restrict__ ws) {
  int bx = blockIdx.x;                 // 64 = 4 c * 16 ig4
  int c = bx >> 4, ig4 = bx & 15;
  int t = threadIdx.x;
  int o = t & 63, il = t >> 6;
  int i = ig4*4 + il;
  int cb = c >> 1;                     // 0: wA = w0-w2, 1: wB = w1+2w2
  int imf = c & 1;                     // odd comp: (Im, Re); even: (Re, -Im)

  uint32_t row32[16];
  #pragma unroll
  for (int d = 0; d < DD; ++d) {
    int b0 = (d*192 + i)*64 + o;       // w[d,kc,i,o]: d stride 12288, kc 4096
    float vre, vim;
    if (cb == 0) {
      vre = w_re[b0] - w_re[b0 + 8192];
      vim = w_im[b0] - w_im[b0 + 8192];
    } else {
      vre = w_re[b0 + 4096] + 2.f*w_re[b0 + 8192];
      vim = w_im[b0 + 4096] + 2.f*w_im[b0 + 8192];
    }
    float q0 = imf ? vim : vre;
    float q1 = imf ? vre : -vim;
    row32[d] = f2bf(q0) | (f2bf(q1) << 16);
  }
  int s = ((i >> 3) ^ (o & 7)) & 7;
  int n = c*4096 + o*64 + s*8 + (i & 7);
  uint4* dst = (uint4*)((uint16_t*)((char*)ws + WS_RHS_B) + (size_t)n*64);
  #pragma unroll
  for (int j = 0; j < 4; ++j) {
    uint4 qv = make_uint4(row32[4*j], row32[4*j+1], row32[4*j+2], row32[4*j+3]);
    dst[j]     = qv;   // h=0
    dst[j + 4] = qv;   // h=1 duplicate (hi/lo ne split reconstructs fp32)
  }
}

// K3a: partial Gram, 25 blocks x 80 v
__global__ void k_norm1(const float* __restrict__ ne_re, const float* __restrict__ ne_im,
                        float* __restrict__ ws) {
  int t = threadIdx.x;
  int d = t >> 4, e = t & 15;
  int v0 = blockIdx.x * 80;
  float gr = 0.f, gi = 0.f;
  for (int v = v0; v < v0 + 80; ++v) {
    float ar = ne_re[v*DD + d], ai = ne_im[v*DD + d];
    float br = ne_re[v*DD + e], bi = ne_im[v*DD + e];
    gr += ar*br + ai*bi;
    gi += ar*bi - ai*br;
  }
  atomicAdd(ws + WS_GRAM_DW + 2*t,     gr);
  atomicAdd(ws + WS_GRAM_DW + 2*t + 1, gi);
}

// K3b: inv_norm
__global__ void k_norm2(float* __restrict__ ws) {
  int t = threadIdx.x;
  float gr = ws[WS_GRAM_DW + 2*t], gi = ws[WS_GRAM_DW + 2*t + 1];
  __shared__ float red[256];
  red[t] = gr*gr + gi*gi;
  __syncthreads();
  for (int k = 128; k > 0; k >>= 1) {
    if (t < k) red[t] += red[t + k];
    __syncthreads();
  }
  if (t == 0) ws[WS_INV_DW] = 1.0f / sqrtf(red[0]);
}

// K4: bias2[u][2*o+half] fp32 (interleaved so k_final stores are linear)
__global__ void k_bias(const float* __restrict__ ne_re, const float* __restrict__ ne_im,
                       const float* __restrict__ b_re, const float* __restrict__ b_im,
                       float* __restrict__ ws) {
  int gid = blockIdx.x * 256 + threadIdx.x;   // 1000 blocks -> 256000
  int u = gid >> 7, idx = gid & 127;
  int o = idx >> 1, half = idx & 1;
  float acc = 0.f;
  #pragma unroll
  for (int d = 0; d < DD; ++d) {
    float nr = ne_re[u*DD + d], ni = ne_im[u*DD + d];
    float pr = b_re[d*CO + o],  pi = b_im[d*CO + o];
    acc += half ? (nr*pi + ni*pr) : (nr*pr - ni*pi);
  }
  ws[WS_BIAS_DW + gid] = acc;
}

// K5: Z partials. grid 1024 = (b:64)x(chunk:16), block 256 = 4 waves x 64 lanes.
__global__ void __launch_bounds__(256, 4)
k_z(const float* __restrict__ x, const float* __restrict__ ne_re,
    const float* __restrict__ ne_im, float* __restrict__ ws) {
  int b = blockIdx.x >> 4, c = blockIdx.x & 15;
  int t = threadIdx.x, w = t >> 6, i = t & 63;
  __shared__ float sred[4 * 2048];

  float zr[DD], zi[DD];
  #pragma unroll
  for (int d = 0; d < DD; ++d) { zr[d] = 0.f; zi[d] = 0.f; }

  int vbase = c * 125;
  int v0 = vbase + ((w * 125) >> 2);
  int v1 = vbase + (((w + 1) * 125) >> 2);
  const float* xp = x + ((size_t)b * VV + v0) * CI + i;
  #pragma unroll 4
  for (int v = v0; v < v1; ++v) {
    float xv = *xp; xp += CI;
    #pragma unroll
    for (int d = 0; d < DD; ++d) {
      zr[d] += ne_re[v*DD + d] * xv;
      zi[d] -= ne_im[v*DD + d] * xv;
    }
  }
  #pragma unroll
  for (int d = 0; d < DD; ++d) {
    sred[w*2048 + d*128 + i*2 + 0] = zr[d];
    sred[w*2048 + d*128 + i*2 + 1] = zi[d];
  }
  __syncthreads();
  float* ZP = ws + WS_ZP_DW;
  #pragma unroll
  for (int k = 0; k < 8; ++k) {
    int j = t + k*256;
    float s = sred[j] + sred[2048 + j] + sred[4096 + j] + sred[6144 + j];
    int d = j >> 7, r = j & 127;
    ZP[(size_t)c*131072 + d*8192 + b*128 + r] = s;
  }
}

// K5b: Z = sum over 16 chunks of ZP
__global__ void k_zred(float* __restrict__ ws) {
  int g = blockIdx.x * 256 + threadIdx.x;
  const float2* ZP2 = (const float2*)(ws + WS_ZP_DW);
  float2 acc = make_float2(0.f, 0.f);
  #pragma unroll
  for (int c = 0; c < 16; ++c) {
    float2 v = ZP2[(size_t)c*65536 + g];
    acc.x += v.x; acc.y += v.y;
  }
  ((float2*)(ws + WS_Z_DW))[g] = acc;
}

// K6: W GEMM -> compact Wc[u][16384]. Interleaved n-tile pairs: tile t covers
// n = nb + 2*n16 + t, so each lane packs (n, n+1) -> dword -> 64B line stores.
__global__ void __launch_bounds__(256, 4)
k_wgemm(float* __restrict__ ws) {
  const uint16_t* NE  = (const uint16_t*)((char*)ws + WS_NE_B);
  const uint16_t* RHS = (const uint16_t*)((char*)ws + WS_RHS_B);
  uint32_t*       W   = (uint32_t*)((char*)ws + WS_W_B);
  int ut = blockIdx.x, nc = blockIdx.y;
  int t = threadIdx.x, w = t >> 6, lane = t & 63;
  int n16 = lane & 15, quad = lane >> 4;
  short8 a[4][2];
  #pragma unroll
  for (int m = 0; m < 4; ++m) {
    int u = ut*64 + m*16 + n16;
    a[m][0] = *(const short8*)(NE + u*64 + quad*8);
    a[m][1] = *(const short8*)(NE + u*64 + 32 + quad*8);
  }
  int nbase = nc*1024 + w*256;
  #pragma unroll 2
  for (int pt = 0; pt < 8; ++pt) {
    int nb = nbase + pt*32;
    const uint16_t* r0 = RHS + (size_t)(nb + 2*n16 + 0)*64 + quad*8;
    const uint16_t* r1 = RHS + (size_t)(nb + 2*n16 + 1)*64 + quad*8;
    short8 b00 = *(const short8*)r0;
    short8 b01 = *(const short8*)(r0 + 32);
    short8 b10 = *(const short8*)r1;
    short8 b11 = *(const short8*)(r1 + 32);
    #pragma unroll
    for (int m = 0; m < 4; ++m) {
      f32x4 acc0 = (f32x4){0.f,0.f,0.f,0.f};
      f32x4 acc1 = (f32x4){0.f,0.f,0.f,0.f};
      acc0 = __builtin_amdgcn_mfma_f32_16x16x32_bf16(a[m][0], b00, acc0, 0, 0, 0);
      acc0 = __builtin_amdgcn_mfma_f32_16x16x32_bf16(a[m][1], b01, acc0, 0, 0, 0);
      acc1 = __builtin_amdgcn_mfma_f32_16x16x32_bf16(a[m][0], b10, acc1, 0, 0, 0);
      acc1 = __builtin_amdgcn_mfma_f32_16x16x32_bf16(a[m][1], b11, acc1, 0, 0, 0);
      #pragma unroll
      for (int r = 0; r < 4; ++r) {
        int u = ut*64 + m*16 + quad*4 + r;
        if (u < VV) {
          uint32_t pk = f2bf(acc0[r]) | (f2bf(acc1[r]) << 16);
          W[(size_t)u*8192 + (nb >> 1) + n16] = pk;
        }
      }
    }
  }
}

// K7: compact U[u][3][64][64] (c: x, yr, yi; swizzle baked), LDS-staged stores.
// grid (125 ug, 16 by), block 256 = 4 b x 64 i, 16 u per block.
//
// R1 restructure (latency theory): the old rolled ul-loop serialized 16
// dependent {x-load -> f2bf -> ds_write} chains (~600 cyc each) at 35%
// occupancy -> 48 us for an ~10 us VALU floor. Now:
//   1. all 16 x loads issued up front (one latency exposure),
//   2. Z loads issued immediately after (L2/L3 resident, land under x),
//   3. x drained to LDS in its own loop (frees 16 VGPRs before y-FMAs),
//   4. ul loop fully unrolled, yr/yi split into 2 accumulators each
//      (dep chain 32 -> 16 FMAs). ne reads stay uniform s_load_dwordx16.
__global__ void __launch_bounds__(256, 4)
k_u(const float* __restrict__ x, const float* __restrict__ ne_re,
    const float* __restrict__ ne_im, float* __restrict__ ws) {
  int ug = blockIdx.x, by = blockIdx.y;
  int t = threadIdx.x, q = t >> 6, i = t & 63;
  int b = by*4 + q;
  float invn = ws[WS_INV_DW];

  // (1) prefetch all 16 x values: independent coalesced 4B loads
  float xv[16];
  {
    const float* xp = x + ((size_t)b*VV + (size_t)ug*16)*CI + i;
    #pragma unroll
    for (int ul = 0; ul < 16; ++ul) xv[ul] = xp[(size_t)ul*CI];
  }

  // (2) Z loads (16 x 8B, cache-resident) — land while x is in flight
  const float* Z = ws + WS_Z_DW;
  float zr[DD], zi[DD];
  #pragma unroll
  for (int d = 0; d < DD; ++d) {
    const float* zp = Z + (size_t)(d*4096 + b*64 + i) * 2;
    zr[d] = zp[0]; zi[d] = zp[1];
  }

  __shared__ uint16_t sStage[192 * 64];       // rr = ul*12 + c*4 + q
  int bkey = b & 7;
  int pos = (((i >> 3) ^ bkey) & 7)*8 + (i & 7);

  // (3) drain x -> LDS (frees xv registers before the FMA-heavy loop)
  #pragma unroll
  for (int ul = 0; ul < 16; ++ul)
    sStage[(ul*12 + 0 + q)*64 + pos] = (uint16_t)f2bf(xv[ul]);

  // (4) y compute, fully unrolled, split accumulators
  #pragma unroll
  for (int ul = 0; ul < 16; ++ul) {
    int u = ug*16 + ul;
    float yra = 0.f, yrb = 0.f, yia = 0.f, yib = 0.f;
    #pragma unroll
    for (int d = 0; d < DD; ++d) {
      float nr = ne_re[u*DD + d], ni = ne_im[u*DD + d];
      yra += nr*zr[d]; yrb += ni*zi[d];
      yia += nr*zi[d]; yib += ni*zr[d];
    }
    float yr = yra - yrb, yi = yia + yib;
    sStage[(ul*12 + 4 + q)*64 + pos] = (uint16_t)f2bf(yr * invn);
    sStage[(ul*12 + 8 + q)*64 + pos] = (uint16_t)f2bf(yi * invn);
  }
  __syncthreads();
  // flush: 192 rows x 128B, 32 rows per pass (8 lanes/row), 6 passes
  uint16_t* U = (uint16_t*)((char*)ws + WS_U_B);
  const uint4* sv = (const uint4*)sStage;
  #pragma unroll
  for (int pass = 0; pass < 6; ++pass) {
    int rr = pass*32 + (t >> 3), l8 = t & 7;
    int ul = rr / 12, rem = rr - ul*12;
    int c = rem >> 2, qq = rem & 3;
    uint4 v = sv[rr*8 + l8];
    *(uint4*)(U + (size_t)(ug*16 + ul)*12288 + c*4096 + (by*4 + qq)*64 + l8*8) = v;
  }
}

// K8: per-node MFMA from compact W,U. LDS pitch 80 elems (160B) -> <=2-way
// bank conflicts. Out stores: wave columns = (8 o)x(re,im) interleaved ->
// 16 consecutive dwords = 64B lines.
#define LP 80           // LDS row pitch (elems)
#define CSTRIDE 5120    // 64*LP: comp stride (elems)
__global__ void __launch_bounds__(512, 2)
k_final(const float* __restrict__ ws, float* __restrict__ out) {
  int u = blockIdx.x, t = threadIdx.x;
  __shared__ __align__(16) uint16_t sW[4 * CSTRIDE];   // 40960B
  __shared__ __align__(16) uint16_t sU[3 * CSTRIDE];   // 30720B
  const uint4* Wg = (const uint4*)((const char*)ws + WS_W_B + (size_t)u*32768);
  const uint4* Ug = (const uint4*)((const char*)ws + WS_U_B + (size_t)u*24576);
  #pragma unroll
  for (int j = 0; j < 4; ++j) {
    int idx = j*512 + t;                       // 2048 chunks of 16B
    int row = idx >> 3, col = idx & 7;
    *(uint4*)&sW[row*LP + col*8] = Wg[idx];
  }
  #pragma unroll
  for (int j = 0; j < 3; ++j) {
    int idx = j*512 + t;                       // 1536 chunks
    int row = idx >> 3, col = idx & 7;
    *(uint4*)&sU[row*LP + col*8] = Ug[idx];
  }
  __syncthreads();

  int w = t >> 6, lane = t & 63;
  int n16 = lane & 15, quad = lane >> 4;
  int o = w*8 + (n16 >> 1), half = n16 & 1;
  int okey = o & 7;
  uint32_t sgnmask = half ? 0u : 0x80008000u;  // negate Bi for re-half at cb=2
  f32x4 acc[4];
  #pragma unroll
  for (int m = 0; m < 4; ++m) acc[m] = (f32x4){0.f,0.f,0.f,0.f};

  #pragma unroll
  for (int ks = 0; ks < 6; ++ks) {
    int cb = ks >> 1;                          // 0,0,1,1,2,2
    int i8 = (ks & 1)*4 + quad;                // logical granule & 7
    int c  = (cb == 0) ? half : ((cb == 1) ? 2 + half : 3 - half);
    int slot = (i8 ^ okey) & 7;
    short8 bfrag = *(const short8*)&sW[c*CSTRIDE + o*LP + slot*8];
    if (cb == 2) {
      uint32_t* bu = (uint32_t*)&bfrag;
      #pragma unroll
      for (int jj = 0; jj < 4; ++jj) bu[jj] ^= sgnmask;
    }
    #pragma unroll
    for (int m = 0; m < 4; ++m) {
      int b = m*16 + n16;
      int aslot = (i8 ^ (b & 7)) & 7;
      short8 afrag = *(const short8*)&sU[cb*CSTRIDE + b*LP + aslot*8];
      acc[m] = __builtin_amdgcn_mfma_f32_16x16x32_bf16(afrag, bfrag, acc[m], 0, 0, 0);
    }
  }

  float bias = ws[WS_BIAS_DW + u*128 + w*16 + n16];
  #pragma unroll
  for (int m = 0; m < 4; ++m) {
    #pragma unroll
    for (int r = 0; r < 4; ++r) {
      int b = m*16 + quad*4 + r;
      out[((size_t)b*VV + u)*128 + w*16 + n16] = acc[m][r] + bias;
    }
  }
}

// ---------------------------------------------------------------------------
extern "C" void kernel_launch(void* const* d_in, const int* in_sizes, int n_in,
                              void* d_out, int out_size, void* d_ws, size_t ws_size,
                              hipStream_t stream) {
  (void)in_sizes; (void)n_in; (void)out_size; (void)ws_size;
  const float* x     = (const float*)d_in[0];
  const float* ne_re = (const float*)d_in[1];
  const float* ne_im = (const float*)d_in[2];
  const float* w_re  = (const float*)d_in[3];
  const float* w_im  = (const float*)d_in[4];
  const float* b_re  = (const float*)d_in[5];
  const float* b_im  = (const float*)d_in[6];
  float* out = (float*)d_out;
  float* ws  = (float*)d_ws;

  k_zero <<<dim3(1),          dim3(256), 0, stream>>>(ws);
  k_ne   <<<dim3(512),        dim3(256), 0, stream>>>(ne_re, ne_im, ws);
  k_rhs  <<<dim3(64),         dim3(256), 0, stream>>>(w_re, w_im, ws);
  k_norm1<<<dim3(25),         dim3(256), 0, stream>>>(ne_re, ne_im, ws);
  k_norm2<<<dim3(1),          dim3(256), 0, stream>>>(ws);
  k_bias <<<dim3(1000),       dim3(256), 0, stream>>>(ne_re, ne_im, b_re, b_im, ws);
  k_z    <<<dim3(1024),       dim3(256), 0, stream>>>(x, ne_re, ne_im, ws);
  k_zred <<<dim3(256),        dim3(256), 0, stream>>>(ws);
  k_wgemm<<<dim3(32, 16),     dim3(256), 0, stream>>>(ws);
  k_u    <<<dim3(125, 16),    dim3(256), 0, stream>>>(x, ne_re, ne_im, ws);
  k_final<<<dim3(VV),         dim3(512), 0, stream>>>(ws, out);
}

// Round 2
// 219.194 us; speedup vs baseline: 1.1026x; 1.0259x over previous
//
#include <hip/hip_runtime.h>
#include <stdint.h>

// Problem constants
#define BB 64
#define VV 2000
#define DD 16
#define CI 64
#define CO 64

// ---- ws layout ----
// dword offsets (fp32 region)
#define WS_INV_DW   0
#define WS_GRAM_DW  8
#define WS_Z_DW     1024                    // float2[16][4096]
#define WS_BIAS_DW  132096                  // fp32 [2000][128]  (idx = 2*o+half)
// byte offsets (bf16 regions), all 16B-aligned
#define WS_NE_B     1552384UL               // bf16 [2048][64]  (hi/lo split ne)
#define WS_RHS_B    1814528UL               // bf16 [16384][64] compact RHS
#define WS_U_B      4960256UL               // bf16 [2000][3][64][64] compact U
#define WS_W_B      54112256UL              // bf16 [2000][4][64][64] compact W
// ZP (k_z partials) aliases the W region: consumed by k_zred BEFORE k_wgemm.
#define WS_ZP_DW    (WS_W_B / 4)

typedef __attribute__((ext_vector_type(8))) short short8;
typedef __attribute__((ext_vector_type(4))) float f32x4;

__device__ __forceinline__ uint32_t f2bf(float f) {
  uint32_t u = __float_as_uint(f);
  return (u + 0x7FFFu + ((u >> 16) & 1u)) >> 16;   // RNE
}

// ---------------------------------------------------------------------------
// K0: zero INV+GRAM (dwords [0,1024))
__global__ void k_zero(float* __restrict__ ws) {
  reinterpret_cast<float4*>(ws)[threadIdx.x] = make_float4(0.f, 0.f, 0.f, 0.f);
}

// K1: NE[u][col] bf16, col = h*32 + d*2 + p; h=0: bf16(ne), h=1: bf16(ne - hi)
__global__ void k_ne(const float* __restrict__ ne_re, const float* __restrict__ ne_im,
                     float* __restrict__ ws) {
  int gid = blockIdx.x * 256 + threadIdx.x;   // 512 blocks -> 131072
  int u = gid >> 6, col = gid & 63;
  int h = col >> 5, kk = col & 31, d = kk >> 1, p = kk & 1;
  float v = 0.f;
  if (u < VV) v = p ? ne_im[u*DD + d] : ne_re[u*DD + d];
  uint32_t hi = f2bf(v);
  uint32_t ov = h ? f2bf(v - __uint_as_float(hi << 16)) : hi;
  ((uint16_t*)((char*)ws + WS_NE_B))[gid] = (uint16_t)ov;
}

// K2: compact RHS[n'][k], n' = c*4096 + o*64 + s*8 + e (granule-swizzle baked:
// s = (ig ^ (o&7))&7). Components c: 0=Ar-maker, 1=Ai, 2=Br, 3=Bi.
// cols k = h*32 + d*2 + p: p0 multiplies nr, p1 multiplies ni.
__global__ void k_rhs(const float* __restrict__ w_re, const float* __restrict__ w_im,
                      float* __restrict__ ws) {
  int bx = blockIdx.x;                 // 64 = 4 c * 16 ig4
  int c = bx >> 4, ig4 = bx & 15;
  int t = threadIdx.x;
  int o = t & 63, il = t >> 6;
  int i = ig4*4 + il;
  int cb = c >> 1;                     // 0: wA = w0-w2, 1: wB = w1+2w2
  int imf = c & 1;                     // odd comp: (Im, Re); even: (Re, -Im)

  uint32_t row32[16];
  #pragma unroll
  for (int d = 0; d < DD; ++d) {
    int b0 = (d*192 + i)*64 + o;       // w[d,kc,i,o]: d stride 12288, kc 4096
    float vre, vim;
    if (cb == 0) {
      vre = w_re[b0] - w_re[b0 + 8192];
      vim = w_im[b0] - w_im[b0 + 8192];
    } else {
      vre = w_re[b0 + 4096] + 2.f*w_re[b0 + 8192];
      vim = w_im[b0 + 4096] + 2.f*w_im[b0 + 8192];
    }
    float q0 = imf ? vim : vre;
    float q1 = imf ? vre : -vim;
    row32[d] = f2bf(q0) | (f2bf(q1) << 16);
  }
  int s = ((i >> 3) ^ (o & 7)) & 7;
  int n = c*4096 + o*64 + s*8 + (i & 7);
  uint4* dst = (uint4*)((uint16_t*)((char*)ws + WS_RHS_B) + (size_t)n*64);
  #pragma unroll
  for (int j = 0; j < 4; ++j) {
    uint4 qv = make_uint4(row32[4*j], row32[4*j+1], row32[4*j+2], row32[4*j+3]);
    dst[j]     = qv;   // h=0
    dst[j + 4] = qv;   // h=1 duplicate (hi/lo ne split reconstructs fp32)
  }
}

// K3a: partial Gram, 25 blocks x 80 v
__global__ void k_norm1(const float* __restrict__ ne_re, const float* __restrict__ ne_im,
                        float* __restrict__ ws) {
  int t = threadIdx.x;
  int d = t >> 4, e = t & 15;
  int v0 = blockIdx.x * 80;
  float gr = 0.f, gi = 0.f;
  for (int v = v0; v < v0 + 80; ++v) {
    float ar = ne_re[v*DD + d], ai = ne_im[v*DD + d];
    float br = ne_re[v*DD + e], bi = ne_im[v*DD + e];
    gr += ar*br + ai*bi;
    gi += ar*bi - ai*br;
  }
  atomicAdd(ws + WS_GRAM_DW + 2*t,     gr);
  atomicAdd(ws + WS_GRAM_DW + 2*t + 1, gi);
}

// K3b: inv_norm
__global__ void k_norm2(float* __restrict__ ws) {
  int t = threadIdx.x;
  float gr = ws[WS_GRAM_DW + 2*t], gi = ws[WS_GRAM_DW + 2*t + 1];
  __shared__ float red[256];
  red[t] = gr*gr + gi*gi;
  __syncthreads();
  for (int k = 128; k > 0; k >>= 1) {
    if (t < k) red[t] += red[t + k];
    __syncthreads();
  }
  if (t == 0) ws[WS_INV_DW] = 1.0f / sqrtf(red[0]);
}

// K4: bias2[u][2*o+half] fp32 (interleaved so k_final stores are linear)
__global__ void k_bias(const float* __restrict__ ne_re, const float* __restrict__ ne_im,
                       const float* __restrict__ b_re, const float* __restrict__ b_im,
                       float* __restrict__ ws) {
  int gid = blockIdx.x * 256 + threadIdx.x;   // 1000 blocks -> 256000
  int u = gid >> 7, idx = gid & 127;
  int o = idx >> 1, half = idx & 1;
  float acc = 0.f;
  #pragma unroll
  for (int d = 0; d < DD; ++d) {
    float nr = ne_re[u*DD + d], ni = ne_im[u*DD + d];
    float pr = b_re[d*CO + o],  pi = b_im[d*CO + o];
    acc += half ? (nr*pi + ni*pr) : (nr*pr - ni*pi);
  }
  ws[WS_BIAS_DW + gid] = acc;
}

// K5: Z partials. grid 1024 = (b:64)x(chunk:16), block 256 = 4 waves x 64 lanes.
//
// R2 restructure (latency theory, same disease as k_u):
//  - OLD: per v-iter, 32 per-lane VECTOR loads of ne (divergence analysis can't
//    prove v uniform because loop bounds derive from t>>6) + 1 serialized x
//    load -> ~1000 VMEM ops/wave, VALUBusy 12%, 41 us for a ~7 us floor.
//  - NEW: (a) readfirstlane(w) makes the v-range provably wave-uniform ->
//    ne reads become s_load_dwordx16 (2 per v); (b) x tile (32 KB contiguous)
//    staged into LDS with 8 independent float4 loads/thread (one latency
//    exposure per block), inner loop reads x via conflict-free ds_read_b32;
//    (c) sred reduction reuses the same 32 KB LDS after a barrier.
__global__ void __launch_bounds__(256, 4)
k_z(const float* __restrict__ x, const float* __restrict__ ne_re,
    const float* __restrict__ ne_im, float* __restrict__ ws) {
  int b = blockIdx.x >> 4, c = blockIdx.x & 15;
  int t = threadIdx.x, lane = t & 63;
  int w = __builtin_amdgcn_readfirstlane(t >> 6);   // wave-uniform in SGPR
  __shared__ __align__(16) float smem[8192];        // 32 KB: x-tile, then sred

  int vbase = c * 125;

  // (b) stage x[b, vbase..vbase+125, :] = 32000 B contiguous into LDS
  {
    const float4* xg = (const float4*)(x + ((size_t)b * VV + vbase) * CI);
    float4 rx[8];
    #pragma unroll
    for (int p = 0; p < 8; ++p) {
      int idx = p * 256 + t;                        // 16B chunk id, 2000 total
      if (idx < 2000) rx[p] = xg[idx];
    }
    #pragma unroll
    for (int p = 0; p < 8; ++p) {
      int idx = p * 256 + t;
      if (idx < 2000) *(float4*)&smem[idx * 4] = rx[p];
    }
  }
  __syncthreads();

  float zr[DD], zi[DD];
  #pragma unroll
  for (int d = 0; d < DD; ++d) { zr[d] = 0.f; zi[d] = 0.f; }

  int lv0 = (w * 125) >> 2;                         // uniform bounds (SGPR)
  int lv1 = ((w + 1) * 125) >> 2;
  #pragma unroll 4
  for (int lv = lv0; lv < lv1; ++lv) {
    float xv = smem[lv * 64 + lane];                // stride-1: conflict-free
    int v = vbase + lv;                             // uniform -> s_load ne
    #pragma unroll
    for (int d = 0; d < DD; ++d) {
      zr[d] += ne_re[v*DD + d] * xv;
      zi[d] -= ne_im[v*DD + d] * xv;
    }
  }
  __syncthreads();                                  // all waves done with x-tile

  #pragma unroll
  for (int d = 0; d < DD; ++d) {
    smem[w*2048 + d*128 + lane*2 + 0] = zr[d];
    smem[w*2048 + d*128 + lane*2 + 1] = zi[d];
  }
  __syncthreads();
  float* ZP = ws + WS_ZP_DW;
  #pragma unroll
  for (int k = 0; k < 8; ++k) {
    int j = t + k*256;
    float s = smem[j] + smem[2048 + j] + smem[4096 + j] + smem[6144 + j];
    int d = j >> 7, r = j & 127;
    ZP[(size_t)c*131072 + d*8192 + b*128 + r] = s;
  }
}

// K5b: Z = sum over 16 chunks of ZP
__global__ void k_zred(float* __restrict__ ws) {
  int g = blockIdx.x * 256 + threadIdx.x;
  const float2* ZP2 = (const float2*)(ws + WS_ZP_DW);
  float2 acc = make_float2(0.f, 0.f);
  #pragma unroll
  for (int c = 0; c < 16; ++c) {
    float2 v = ZP2[(size_t)c*65536 + g];
    acc.x += v.x; acc.y += v.y;
  }
  ((float2*)(ws + WS_Z_DW))[g] = acc;
}

// K6: W GEMM -> compact Wc[u][16384]. Interleaved n-tile pairs: tile t covers
// n = nb + 2*n16 + t, so each lane packs (n, n+1) -> dword -> 64B line stores.
__global__ void __launch_bounds__(256, 4)
k_wgemm(float* __restrict__ ws) {
  const uint16_t* NE  = (const uint16_t*)((char*)ws + WS_NE_B);
  const uint16_t* RHS = (const uint16_t*)((char*)ws + WS_RHS_B);
  uint32_t*       W   = (uint32_t*)((char*)ws + WS_W_B);
  int ut = blockIdx.x, nc = blockIdx.y;
  int t = threadIdx.x, w = t >> 6, lane = t & 63;
  int n16 = lane & 15, quad = lane >> 4;
  short8 a[4][2];
  #pragma unroll
  for (int m = 0; m < 4; ++m) {
    int u = ut*64 + m*16 + n16;
    a[m][0] = *(const short8*)(NE + u*64 + quad*8);
    a[m][1] = *(const short8*)(NE + u*64 + 32 + quad*8);
  }
  int nbase = nc*1024 + w*256;
  #pragma unroll 2
  for (int pt = 0; pt < 8; ++pt) {
    int nb = nbase + pt*32;
    const uint16_t* r0 = RHS + (size_t)(nb + 2*n16 + 0)*64 + quad*8;
    const uint16_t* r1 = RHS + (size_t)(nb + 2*n16 + 1)*64 + quad*8;
    short8 b00 = *(const short8*)r0;
    short8 b01 = *(const short8*)(r0 + 32);
    short8 b10 = *(const short8*)r1;
    short8 b11 = *(const short8*)(r1 + 32);
    #pragma unroll
    for (int m = 0; m < 4; ++m) {
      f32x4 acc0 = (f32x4){0.f,0.f,0.f,0.f};
      f32x4 acc1 = (f32x4){0.f,0.f,0.f,0.f};
      acc0 = __builtin_amdgcn_mfma_f32_16x16x32_bf16(a[m][0], b00, acc0, 0, 0, 0);
      acc0 = __builtin_amdgcn_mfma_f32_16x16x32_bf16(a[m][1], b01, acc0, 0, 0, 0);
      acc1 = __builtin_amdgcn_mfma_f32_16x16x32_bf16(a[m][0], b10, acc1, 0, 0, 0);
      acc1 = __builtin_amdgcn_mfma_f32_16x16x32_bf16(a[m][1], b11, acc1, 0, 0, 0);
      #pragma unroll
      for (int r = 0; r < 4; ++r) {
        int u = ut*64 + m*16 + quad*4 + r;
        if (u < VV) {
          uint32_t pk = f2bf(acc0[r]) | (f2bf(acc1[r]) << 16);
          W[(size_t)u*8192 + (nb >> 1) + n16] = pk;
        }
      }
    }
  }
}

// K7: compact U[u][3][64][64] (c: x, yr, yi; swizzle baked), LDS-staged stores.
// grid (125 ug, 16 by), block 256 = 4 b x 64 i, 16 u per block.
// R1 restructure: prefetch x16, Z loads behind, drain x->LDS, unrolled y loop.
__global__ void __launch_bounds__(256, 4)
k_u(const float* __restrict__ x, const float* __restrict__ ne_re,
    const float* __restrict__ ne_im, float* __restrict__ ws) {
  int ug = blockIdx.x, by = blockIdx.y;
  int t = threadIdx.x, q = t >> 6, i = t & 63;
  int b = by*4 + q;
  float invn = ws[WS_INV_DW];

  // (1) prefetch all 16 x values: independent coalesced 4B loads
  float xv[16];
  {
    const float* xp = x + ((size_t)b*VV + (size_t)ug*16)*CI + i;
    #pragma unroll
    for (int ul = 0; ul < 16; ++ul) xv[ul] = xp[(size_t)ul*CI];
  }

  // (2) Z loads (16 x 8B, cache-resident) — land while x is in flight
  const float* Z = ws + WS_Z_DW;
  float zr[DD], zi[DD];
  #pragma unroll
  for (int d = 0; d < DD; ++d) {
    const float* zp = Z + (size_t)(d*4096 + b*64 + i) * 2;
    zr[d] = zp[0]; zi[d] = zp[1];
  }

  __shared__ uint16_t sStage[192 * 64];       // rr = ul*12 + c*4 + q
  int bkey = b & 7;
  int pos = (((i >> 3) ^ bkey) & 7)*8 + (i & 7);

  // (3) drain x -> LDS (frees xv registers before the FMA-heavy loop)
  #pragma unroll
  for (int ul = 0; ul < 16; ++ul)
    sStage[(ul*12 + 0 + q)*64 + pos] = (uint16_t)f2bf(xv[ul]);

  // (4) y compute, fully unrolled, split accumulators
  #pragma unroll
  for (int ul = 0; ul < 16; ++ul) {
    int u = ug*16 + ul;
    float yra = 0.f, yrb = 0.f, yia = 0.f, yib = 0.f;
    #pragma unroll
    for (int d = 0; d < DD; ++d) {
      float nr = ne_re[u*DD + d], ni = ne_im[u*DD + d];
      yra += nr*zr[d]; yrb += ni*zi[d];
      yia += nr*zi[d]; yib += ni*zr[d];
    }
    float yr = yra - yrb, yi = yia + yib;
    sStage[(ul*12 + 4 + q)*64 + pos] = (uint16_t)f2bf(yr * invn);
    sStage[(ul*12 + 8 + q)*64 + pos] = (uint16_t)f2bf(yi * invn);
  }
  __syncthreads();
  // flush: 192 rows x 128B, 32 rows per pass (8 lanes/row), 6 passes
  uint16_t* U = (uint16_t*)((char*)ws + WS_U_B);
  const uint4* sv = (const uint4*)sStage;
  #pragma unroll
  for (int pass = 0; pass < 6; ++pass) {
    int rr = pass*32 + (t >> 3), l8 = t & 7;
    int ul = rr / 12, rem = rr - ul*12;
    int c = rem >> 2, qq = rem & 3;
    uint4 v = sv[rr*8 + l8];
    *(uint4*)(U + (size_t)(ug*16 + ul)*12288 + c*4096 + (by*4 + qq)*64 + l8*8) = v;
  }
}

// K8: per-node MFMA from compact W,U. LDS pitch 80 elems (160B) -> <=2-way
// bank conflicts. Out stores: wave columns = (8 o)x(re,im) interleaved ->
// 16 consecutive dwords = 64B lines.
#define LP 80           // LDS row pitch (elems)
#define CSTRIDE 5120    // 64*LP: comp stride (elems)
__global__ void __launch_bounds__(512, 2)
k_final(const float* __restrict__ ws, float* __restrict__ out) {
  int u = blockIdx.x, t = threadIdx.x;
  __shared__ __align__(16) uint16_t sW[4 * CSTRIDE];   // 40960B
  __shared__ __align__(16) uint16_t sU[3 * CSTRIDE];   // 30720B
  const uint4* Wg = (const uint4*)((const char*)ws + WS_W_B + (size_t)u*32768);
  const uint4* Ug = (const uint4*)((const char*)ws + WS_U_B + (size_t)u*24576);
  #pragma unroll
  for (int j = 0; j < 4; ++j) {
    int idx = j*512 + t;                       // 2048 chunks of 16B
    int row = idx >> 3, col = idx & 7;
    *(uint4*)&sW[row*LP + col*8] = Wg[idx];
  }
  #pragma unroll
  for (int j = 0; j < 3; ++j) {
    int idx = j*512 + t;                       // 1536 chunks
    int row = idx >> 3, col = idx & 7;
    *(uint4*)&sU[row*LP + col*8] = Ug[idx];
  }
  __syncthreads();

  int w = t >> 6, lane = t & 63;
  int n16 = lane & 15, quad = lane >> 4;
  int o = w*8 + (n16 >> 1), half = n16 & 1;
  int okey = o & 7;
  uint32_t sgnmask = half ? 0u : 0x80008000u;  // negate Bi for re-half at cb=2
  f32x4 acc[4];
  #pragma unroll
  for (int m = 0; m < 4; ++m) acc[m] = (f32x4){0.f,0.f,0.f,0.f};

  #pragma unroll
  for (int ks = 0; ks < 6; ++ks) {
    int cb = ks >> 1;                          // 0,0,1,1,2,2
    int i8 = (ks & 1)*4 + quad;                // logical granule & 7
    int c  = (cb == 0) ? half : ((cb == 1) ? 2 + half : 3 - half);
    int slot = (i8 ^ okey) & 7;
    short8 bfrag = *(const short8*)&sW[c*CSTRIDE + o*LP + slot*8];
    if (cb == 2) {
      uint32_t* bu = (uint32_t*)&bfrag;
      #pragma unroll
      for (int jj = 0; jj < 4; ++jj) bu[jj] ^= sgnmask;
    }
    #pragma unroll
    for (int m = 0; m < 4; ++m) {
      int b = m*16 + n16;
      int aslot = (i8 ^ (b & 7)) & 7;
      short8 afrag = *(const short8*)&sU[cb*CSTRIDE + b*LP + aslot*8];
      acc[m] = __builtin_amdgcn_mfma_f32_16x16x32_bf16(afrag, bfrag, acc[m], 0, 0, 0);
    }
  }

  float bias = ws[WS_BIAS_DW + u*128 + w*16 + n16];
  #pragma unroll
  for (int m = 0; m < 4; ++m) {
    #pragma unroll
    for (int r = 0; r < 4; ++r) {
      int b = m*16 + quad*4 + r;
      out[((size_t)b*VV + u)*128 + w*16 + n16] = acc[m][r] + bias;
    }
  }
}

// ---------------------------------------------------------------------------
extern "C" void kernel_launch(void* const* d_in, const int* in_sizes, int n_in,
                              void* d_out, int out_size, void* d_ws, size_t ws_size,
                              hipStream_t stream) {
  (void)in_sizes; (void)n_in; (void)out_size; (void)ws_size;
  const float* x     = (const float*)d_in[0];
  const float* ne_re = (const float*)d_in[1];
  const float* ne_im = (const float*)d_in[2];
  const float* w_re  = (const float*)d_in[3];
  const float* w_im  = (const float*)d_in[4];
  const float* b_re  = (const float*)d_in[5];
  const float* b_im  = (const float*)d_in[6];
  float* out = (float*)d_out;
  float* ws  = (float*)d_ws;

  k_zero <<<dim3(1),          dim3(256), 0, stream>>>(ws);
  k_ne   <<<dim3(512),        dim3(256), 0, stream>>>(ne_re, ne_im, ws);
  k_rhs  <<<dim3(64),         dim3(256), 0, stream>>>(w_re, w_im, ws);
  k_norm1<<<dim3(25),         dim3(256), 0, stream>>>(ne_re, ne_im, ws);
  k_norm2<<<dim3(1),          dim3(256), 0, stream>>>(ws);
  k_bias <<<dim3(1000),       dim3(256), 0, stream>>>(ne_re, ne_im, b_re, b_im, ws);
  k_z    <<<dim3(1024),       dim3(256), 0, stream>>>(x, ne_re, ne_im, ws);
  k_zred <<<dim3(256),        dim3(256), 0, stream>>>(ws);
  k_wgemm<<<dim3(32, 16),     dim3(256), 0, stream>>>(ws);
  k_u    <<<dim3(125, 16),    dim3(256), 0, stream>>>(x, ne_re, ne_im, ws);
  k_final<<<dim3(VV),         dim3(512), 0, stream>>>(ws, out);
}

// Round 5
// 198.015 us; speedup vs baseline: 1.2205x; 1.1070x over previous
//
#include <hip/hip_runtime.h>
#include <stdint.h>

// Problem constants
#define BB 64
#define VV 2000
#define DD 16
#define CI 64
#define CO 64

// ---- ws layout ----
// dword offsets (fp32 region)
#define WS_INV_DW   0
#define WS_Z_DW     1024                    // float2[16][4096]
#define WS_BIAS_DW  132096                  // fp32 [2000][128]  (idx = 2*o+half)
// byte offsets (bf16 regions), all 16B-aligned
#define WS_NE_B     1552384UL               // bf16 [2048][64]  (hi/lo split ne)
#define WS_RHS_B    1814528UL               // bf16 [16384][64] compact RHS
#define WS_U_B      4960256UL               // bf16 [2000][3][64][64] compact U
#define WS_W_B      54112256UL              // bf16 [2000][4][64][64] compact W
// ZP (k_z partials, 8.4 MB) and NP (norm1 partials, 51 KB) alias the U region:
// written by k_front, consumed by k_mid, then overwritten by k_u. This keeps
// them OUT of the W region so k_mid can run zred+norm2+wgemm concurrently.
#define WS_ZP_DW    (WS_U_B / 4)            // 1240064
#define WS_NP_DW    (WS_ZP_DW + 2097152)    // 25 blocks x 512 floats

typedef __attribute__((ext_vector_type(8))) short short8;
typedef __attribute__((ext_vector_type(4))) float f32x4;

__device__ __forceinline__ uint32_t f2bf(float f) {
  uint32_t u = __float_as_uint(f);
  return (u + 0x7FFFu + ((u >> 16) & 1u)) >> 16;   // RNE
}

// ---------------------------------------------------------------------------
// Component bodies (device-inline), fused into k_front / k_mid by blockIdx
// range. All components use 256-thread blocks. Dependencies:
//   k_front: {z, ne, rhs, norm1-partials, bias}   (mutually independent)
//   k_mid:   {wgemm, zred, norm2}                 (all need only k_front)
//   k_u:     needs Z + INV (k_mid)
//   k_final: needs W (k_mid) + U (k_u) + bias (k_front)
// ---------------------------------------------------------------------------

// z: Z partials. 1024 virtual blocks = (b:64)x(chunk:16).
// R2 structure: wave-uniform v-range (scalar ne loads), x tile staged in LDS.
__device__ __forceinline__ void body_z(int bz, int t,
    const float* __restrict__ x, const float* __restrict__ ne_re,
    const float* __restrict__ ne_im, float* __restrict__ ws) {
  int b = bz >> 4, c = bz & 15;
  int lane = t & 63;
  int w = __builtin_amdgcn_readfirstlane(t >> 6);   // wave-uniform in SGPR
  __shared__ __align__(16) float smem[8192];        // 32 KB: x-tile, then sred

  int vbase = c * 125;

  // stage x[b, vbase..vbase+125, :] = 32000 B contiguous into LDS
  {
    const float4* xg = (const float4*)(x + ((size_t)b * VV + vbase) * CI);
    float4 rx[8];
    #pragma unroll
    for (int p = 0; p < 8; ++p) {
      int idx = p * 256 + t;                        // 16B chunk id, 2000 total
      if (idx < 2000) rx[p] = xg[idx];
    }
    #pragma unroll
    for (int p = 0; p < 8; ++p) {
      int idx = p * 256 + t;
      if (idx < 2000) *(float4*)&smem[idx * 4] = rx[p];
    }
  }
  __syncthreads();

  float zr[DD], zi[DD];
  #pragma unroll
  for (int d = 0; d < DD; ++d) { zr[d] = 0.f; zi[d] = 0.f; }

  int lv0 = (w * 125) >> 2;                         // uniform bounds (SGPR)
  int lv1 = ((w + 1) * 125) >> 2;
  #pragma unroll 4
  for (int lv = lv0; lv < lv1; ++lv) {
    float xv = smem[lv * 64 + lane];                // stride-1: conflict-free
    int v = vbase + lv;                             // uniform -> s_load ne
    #pragma unroll
    for (int d = 0; d < DD; ++d) {
      zr[d] += ne_re[v*DD + d] * xv;
      zi[d] -= ne_im[v*DD + d] * xv;
    }
  }
  __syncthreads();                                  // all waves done with x-tile

  #pragma unroll
  for (int d = 0; d < DD; ++d) {
    smem[w*2048 + d*128 + lane*2 + 0] = zr[d];
    smem[w*2048 + d*128 + lane*2 + 1] = zi[d];
  }
  __syncthreads();
  float* ZP = ws + WS_ZP_DW;
  #pragma unroll
  for (int k = 0; k < 8; ++k) {
    int j = t + k*256;
    float s = smem[j] + smem[2048 + j] + smem[4096 + j] + smem[6144 + j];
    int d = j >> 7, r = j & 127;
    ZP[(size_t)c*131072 + d*8192 + b*128 + r] = s;
  }
}

// ne: NE[u][col] bf16, col = h*32 + d*2 + p; h=0: bf16(ne), h=1: bf16(ne - hi)
__device__ __forceinline__ void body_ne(int bx, int t,
    const float* __restrict__ ne_re, const float* __restrict__ ne_im,
    float* __restrict__ ws) {
  int gid = bx * 256 + t;                     // 512 blocks -> 131072
  int u = gid >> 6, col = gid & 63;
  int h = col >> 5, kk = col & 31, d = kk >> 1, p = kk & 1;
  float v = 0.f;
  if (u < VV) v = p ? ne_im[u*DD + d] : ne_re[u*DD + d];
  uint32_t hi = f2bf(v);
  uint32_t ov = h ? f2bf(v - __uint_as_float(hi << 16)) : hi;
  ((uint16_t*)((char*)ws + WS_NE_B))[gid] = (uint16_t)ov;
}

// rhs: compact RHS[n'][k], n' = c*4096 + o*64 + s*8 + e (granule-swizzle baked)
__device__ __forceinline__ void body_rhs(int bx, int t,
    const float* __restrict__ w_re, const float* __restrict__ w_im,
    float* __restrict__ ws) {
  int c = bx >> 4, ig4 = bx & 15;
  int o = t & 63, il = t >> 6;
  int i = ig4*4 + il;
  int cb = c >> 1;                     // 0: wA = w0-w2, 1: wB = w1+2w2
  int imf = c & 1;                     // odd comp: (Im, Re); even: (Re, -Im)

  uint32_t row32[16];
  #pragma unroll
  for (int d = 0; d < DD; ++d) {
    int b0 = (d*192 + i)*64 + o;       // w[d,kc,i,o]: d stride 12288, kc 4096
    float vre, vim;
    if (cb == 0) {
      vre = w_re[b0] - w_re[b0 + 8192];
      vim = w_im[b0] - w_im[b0 + 8192];
    } else {
      vre = w_re[b0 + 4096] + 2.f*w_re[b0 + 8192];
      vim = w_im[b0 + 4096] + 2.f*w_im[b0 + 8192];
    }
    float q0 = imf ? vim : vre;
    float q1 = imf ? vre : -vim;
    row32[d] = f2bf(q0) | (f2bf(q1) << 16);
  }
  int s = ((i >> 3) ^ (o & 7)) & 7;
  int n = c*4096 + o*64 + s*8 + (i & 7);
  uint4* dst = (uint4*)((uint16_t*)((char*)ws + WS_RHS_B) + (size_t)n*64);
  #pragma unroll
  for (int j = 0; j < 4; ++j) {
    uint4 qv = make_uint4(row32[4*j], row32[4*j+1], row32[4*j+2], row32[4*j+3]);
    dst[j]     = qv;   // h=0
    dst[j + 4] = qv;   // h=1 duplicate (hi/lo ne split reconstructs fp32)
  }
}

// norm1: partial Gram, 25 virtual blocks x 80 v. Writes per-block partials to
// NP (no atomics, no pre-zeroing needed -> k_zero deleted).
__device__ __forceinline__ void body_norm1(int bx, int t,
    const float* __restrict__ ne_re, const float* __restrict__ ne_im,
    float* __restrict__ ws) {
  int d = t >> 4, e = t & 15;
  int v0 = bx * 80;
  float gr = 0.f, gi = 0.f;
  for (int v = v0; v < v0 + 80; ++v) {
    float ar = ne_re[v*DD + d], ai = ne_im[v*DD + d];
    float br = ne_re[v*DD + e], bi = ne_im[v*DD + e];
    gr += ar*br + ai*bi;
    gi += ar*bi - ai*br;
  }
  float* NP = ws + WS_NP_DW;
  NP[bx*512 + 2*t]     = gr;
  NP[bx*512 + 2*t + 1] = gi;
}

// bias: bias2[u][2*o+half] fp32 (interleaved so k_final stores are linear)
__device__ __forceinline__ void body_bias(int bx, int t,
    const float* __restrict__ ne_re, const float* __restrict__ ne_im,
    const float* __restrict__ b_re, const float* __restrict__ b_im,
    float* __restrict__ ws) {
  int gid = bx * 256 + t;                     // 1000 blocks -> 256000
  int u = gid >> 7, idx = gid & 127;
  int o = idx >> 1, half = idx & 1;
  float acc = 0.f;
  #pragma unroll
  for (int d = 0; d < DD; ++d) {
    float nr = ne_re[u*DD + d], ni = ne_im[u*DD + d];
    float pr = b_re[d*CO + o],  pi = b_im[d*CO + o];
    acc += half ? (nr*pi + ni*pr) : (nr*pr - ni*pi);
  }
  ws[WS_BIAS_DW + gid] = acc;
}

// wgemm: W GEMM -> compact Wc[u][16384].
__device__ __forceinline__ void body_wgemm(int bx, int t, float* __restrict__ ws) {
  const uint16_t* NE  = (const uint16_t*)((char*)ws + WS_NE_B);
  const uint16_t* RHS = (const uint16_t*)((char*)ws + WS_RHS_B);
  uint32_t*       W   = (uint32_t*)((char*)ws + WS_W_B);
  int ut = bx & 31, nc = bx >> 5;
  int w = t >> 6, lane = t & 63;
  int n16 = lane & 15, quad = lane >> 4;
  short8 a[4][2];
  #pragma unroll
  for (int m = 0; m < 4; ++m) {
    int u = ut*64 + m*16 + n16;
    a[m][0] = *(const short8*)(NE + u*64 + quad*8);
    a[m][1] = *(const short8*)(NE + u*64 + 32 + quad*8);
  }
  int nbase = nc*1024 + w*256;
  #pragma unroll 2
  for (int pt = 0; pt < 8; ++pt) {
    int nb = nbase + pt*32;
    const uint16_t* r0 = RHS + (size_t)(nb + 2*n16 + 0)*64 + quad*8;
    const uint16_t* r1 = RHS + (size_t)(nb + 2*n16 + 1)*64 + quad*8;
    short8 b00 = *(const short8*)r0;
    short8 b01 = *(const short8*)(r0 + 32);
    short8 b10 = *(const short8*)r1;
    short8 b11 = *(const short8*)(r1 + 32);
    #pragma unroll
    for (int m = 0; m < 4; ++m) {
      f32x4 acc0 = (f32x4){0.f,0.f,0.f,0.f};
      f32x4 acc1 = (f32x4){0.f,0.f,0.f,0.f};
      acc0 = __builtin_amdgcn_mfma_f32_16x16x32_bf16(a[m][0], b00, acc0, 0, 0, 0);
      acc0 = __builtin_amdgcn_mfma_f32_16x16x32_bf16(a[m][1], b01, acc0, 0, 0, 0);
      acc1 = __builtin_amdgcn_mfma_f32_16x16x32_bf16(a[m][0], b10, acc1, 0, 0, 0);
      acc1 = __builtin_amdgcn_mfma_f32_16x16x32_bf16(a[m][1], b11, acc1, 0, 0, 0);
      #pragma unroll
      for (int r = 0; r < 4; ++r) {
        int u = ut*64 + m*16 + quad*4 + r;
        if (u < VV) {
          uint32_t pk = f2bf(acc0[r]) | (f2bf(acc1[r]) << 16);
          W[(size_t)u*8192 + (nb >> 1) + n16] = pk;
        }
      }
    }
  }
}

// zred: Z = sum over 16 chunks of ZP. 256 virtual blocks.
__device__ __forceinline__ void body_zred(int bx, int t, float* __restrict__ ws) {
  int g = bx * 256 + t;
  const float2* ZP2 = (const float2*)(ws + WS_ZP_DW);
  float2 acc = make_float2(0.f, 0.f);
  #pragma unroll
  for (int c = 0; c < 16; ++c) {
    float2 v = ZP2[(size_t)c*65536 + g];
    acc.x += v.x; acc.y += v.y;
  }
  ((float2*)(ws + WS_Z_DW))[g] = acc;
}

// norm2: reduce NP partials -> INV. 1 virtual block.
__device__ __forceinline__ void body_norm2(int t, float* __restrict__ ws) {
  const float* NP = ws + WS_NP_DW;
  float gr = 0.f, gi = 0.f;
  #pragma unroll
  for (int p = 0; p < 25; ++p) {
    gr += NP[p*512 + 2*t];
    gi += NP[p*512 + 2*t + 1];
  }
  __shared__ float red[256];
  red[t] = gr*gr + gi*gi;
  __syncthreads();
  for (int k = 128; k > 0; k >>= 1) {
    if (t < k) red[t] += red[t + k];
    __syncthreads();
  }
  if (t == 0) ws[WS_INV_DW] = 1.0f / sqrtf(red[0]);
}

// ---------------------------------------------------------------------------
// Fused dispatchers
// ---------------------------------------------------------------------------

// k_front: 2625 blocks. z [0,1024) | ne [1024,1536) | rhs [1536,1600) |
//          norm1 [1600,1625) | bias [1625,2625). z first: it's the long pole.
__global__ void __launch_bounds__(256, 4)
k_front(const float* __restrict__ x, const float* __restrict__ ne_re,
        const float* __restrict__ ne_im, const float* __restrict__ w_re,
        const float* __restrict__ w_im, const float* __restrict__ b_re,
        const float* __restrict__ b_im, float* __restrict__ ws) {
  int bx = blockIdx.x, t = threadIdx.x;
  if (bx < 1024) {
    body_z(bx, t, x, ne_re, ne_im, ws);
  } else if (bx < 1536) {
    body_ne(bx - 1024, t, ne_re, ne_im, ws);
  } else if (bx < 1600) {
    body_rhs(bx - 1536, t, w_re, w_im, ws);
  } else if (bx < 1625) {
    body_norm1(bx - 1600, t, ne_re, ne_im, ws);
  } else {
    body_bias(bx - 1625, t, ne_re, ne_im, b_re, b_im, ws);
  }
}

// k_mid: 769 blocks. wgemm [0,512) | zred [512,768) | norm2 768.
// ZP/NP live in the U region (not W), so wgemm's W writes don't race zred.
__global__ void __launch_bounds__(256, 4)
k_mid(float* __restrict__ ws) {
  int bx = blockIdx.x, t = threadIdx.x;
  if (bx < 512) {
    body_wgemm(bx, t, ws);
  } else if (bx < 768) {
    body_zred(bx - 512, t, ws);
  } else {
    body_norm2(t, ws);
  }
}

// K7: compact U[u][3][64][64] (c: x, yr, yi; swizzle baked), LDS-staged stores.
// grid (125 ug, 16 by), block 256 = 4 b x 64 i, 16 u per block.
// R1 restructure: prefetch x16, Z loads behind, drain x->LDS, unrolled y loop.
__global__ void __launch_bounds__(256, 4)
k_u(const float* __restrict__ x, const float* __restrict__ ne_re,
    const float* __restrict__ ne_im, float* __restrict__ ws) {
  int ug = blockIdx.x, by = blockIdx.y;
  int t = threadIdx.x, q = t >> 6, i = t & 63;
  int b = by*4 + q;
  float invn = ws[WS_INV_DW];

  // (1) prefetch all 16 x values: independent coalesced 4B loads
  float xv[16];
  {
    const float* xp = x + ((size_t)b*VV + (size_t)ug*16)*CI + i;
    #pragma unroll
    for (int ul = 0; ul < 16; ++ul) xv[ul] = xp[(size_t)ul*CI];
  }

  // (2) Z loads (16 x 8B, cache-resident) — land while x is in flight
  const float* Z = ws + WS_Z_DW;
  float zr[DD], zi[DD];
  #pragma unroll
  for (int d = 0; d < DD; ++d) {
    const float* zp = Z + (size_t)(d*4096 + b*64 + i) * 2;
    zr[d] = zp[0]; zi[d] = zp[1];
  }

  __shared__ uint16_t sStage[192 * 64];       // rr = ul*12 + c*4 + q
  int bkey = b & 7;
  int pos = (((i >> 3) ^ bkey) & 7)*8 + (i & 7);

  // (3) drain x -> LDS (frees xv registers before the FMA-heavy loop)
  #pragma unroll
  for (int ul = 0; ul < 16; ++ul)
    sStage[(ul*12 + 0 + q)*64 + pos] = (uint16_t)f2bf(xv[ul]);

  // (4) y compute, fully unrolled, split accumulators
  #pragma unroll
  for (int ul = 0; ul < 16; ++ul) {
    int u = ug*16 + ul;
    float yra = 0.f, yrb = 0.f, yia = 0.f, yib = 0.f;
    #pragma unroll
    for (int d = 0; d < DD; ++d) {
      float nr = ne_re[u*DD + d], ni = ne_im[u*DD + d];
      yra += nr*zr[d]; yrb += ni*zi[d];
      yia += nr*zi[d]; yib += ni*zr[d];
    }
    float yr = yra - yrb, yi = yia + yib;
    sStage[(ul*12 + 4 + q)*64 + pos] = (uint16_t)f2bf(yr * invn);
    sStage[(ul*12 + 8 + q)*64 + pos] = (uint16_t)f2bf(yi * invn);
  }
  __syncthreads();
  // flush: 192 rows x 128B, 32 rows per pass (8 lanes/row), 6 passes
  uint16_t* U = (uint16_t*)((char*)ws + WS_U_B);
  const uint4* sv = (const uint4*)sStage;
  #pragma unroll
  for (int pass = 0; pass < 6; ++pass) {
    int rr = pass*32 + (t >> 3), l8 = t & 7;
    int ul = rr / 12, rem = rr - ul*12;
    int c = rem >> 2, qq = rem & 3;
    uint4 v = sv[rr*8 + l8];
    *(uint4*)(U + (size_t)(ug*16 + ul)*12288 + c*4096 + (by*4 + qq)*64 + l8*8) = v;
  }
}

// K8: per-node MFMA from compact W,U. LDS pitch 80 elems (160B) -> <=2-way
// bank conflicts. Out stores: wave columns = (8 o)x(re,im) interleaved ->
// 16 consecutive dwords = 64B lines.
#define LP 80           // LDS row pitch (elems)
#define CSTRIDE 5120    // 64*LP: comp stride (elems)
__global__ void __launch_bounds__(512, 2)
k_final(const float* __restrict__ ws, float* __restrict__ out) {
  int u = blockIdx.x, t = threadIdx.x;
  __shared__ __align__(16) uint16_t sW[4 * CSTRIDE];   // 40960B
  __shared__ __align__(16) uint16_t sU[3 * CSTRIDE];   // 30720B
  const uint4* Wg = (const uint4*)((const char*)ws + WS_W_B + (size_t)u*32768);
  const uint4* Ug = (const uint4*)((const char*)ws + WS_U_B + (size_t)u*24576);
  #pragma unroll
  for (int j = 0; j < 4; ++j) {
    int idx = j*512 + t;                       // 2048 chunks of 16B
    int row = idx >> 3, col = idx & 7;
    *(uint4*)&sW[row*LP + col*8] = Wg[idx];
  }
  #pragma unroll
  for (int j = 0; j < 3; ++j) {
    int idx = j*512 + t;                       // 1536 chunks
    int row = idx >> 3, col = idx & 7;
    *(uint4*)&sU[row*LP + col*8] = Ug[idx];
  }
  __syncthreads();

  int w = t >> 6, lane = t & 63;
  int n16 = lane & 15, quad = lane >> 4;
  int o = w*8 + (n16 >> 1), half = n16 & 1;
  int okey = o & 7;
  uint32_t sgnmask = half ? 0u : 0x80008000u;  // negate Bi for re-half at cb=2
  f32x4 acc[4];
  #pragma unroll
  for (int m = 0; m < 4; ++m) acc[m] = (f32x4){0.f,0.f,0.f,0.f};

  #pragma unroll
  for (int ks = 0; ks < 6; ++ks) {
    int cb = ks >> 1;                          // 0,0,1,1,2,2
    int i8 = (ks & 1)*4 + quad;                // logical granule & 7
    int c  = (cb == 0) ? half : ((cb == 1) ? 2 + half : 3 - half);
    int slot = (i8 ^ okey) & 7;
    short8 bfrag = *(const short8*)&sW[c*CSTRIDE + o*LP + slot*8];
    if (cb == 2) {
      uint32_t* bu = (uint32_t*)&bfrag;
      #pragma unroll
      for (int jj = 0; jj < 4; ++jj) bu[jj] ^= sgnmask;
    }
    #pragma unroll
    for (int m = 0; m < 4; ++m) {
      int b = m*16 + n16;
      int aslot = (i8 ^ (b & 7)) & 7;
      short8 afrag = *(const short8*)&sU[cb*CSTRIDE + b*LP + aslot*8];
      acc[m] = __builtin_amdgcn_mfma_f32_16x16x32_bf16(afrag, bfrag, acc[m], 0, 0, 0);
    }
  }

  float bias = ws[WS_BIAS_DW + u*128 + w*16 + n16];
  #pragma unroll
  for (int m = 0; m < 4; ++m) {
    #pragma unroll
    for (int r = 0; r < 4; ++r) {
      int b = m*16 + quad*4 + r;
      out[((size_t)b*VV + u)*128 + w*16 + n16] = acc[m][r] + bias;
    }
  }
}

// ---------------------------------------------------------------------------
extern "C" void kernel_launch(void* const* d_in, const int* in_sizes, int n_in,
                              void* d_out, int out_size, void* d_ws, size_t ws_size,
                              hipStream_t stream) {
  (void)in_sizes; (void)n_in; (void)out_size; (void)ws_size;
  const float* x     = (const float*)d_in[0];
  const float* ne_re = (const float*)d_in[1];
  const float* ne_im = (const float*)d_in[2];
  const float* w_re  = (const float*)d_in[3];
  const float* w_im  = (const float*)d_in[4];
  const float* b_re  = (const float*)d_in[5];
  const float* b_im  = (const float*)d_in[6];
  float* out = (float*)d_out;
  float* ws  = (float*)d_ws;

  k_front<<<dim3(2625),    dim3(256), 0, stream>>>(x, ne_re, ne_im, w_re, w_im,
                                                   b_re, b_im, ws);
  k_mid  <<<dim3(769),     dim3(256), 0, stream>>>(ws);
  k_u    <<<dim3(125, 16), dim3(256), 0, stream>>>(x, ne_re, ne_im, ws);
  k_final<<<dim3(VV),      dim3(512), 0, stream>>>(ws, out);
}

// Round 7
// 188.717 us; speedup vs baseline: 1.2807x; 1.0493x over previous
//
#include <hip/hip_runtime.h>
#include <stdint.h>

// Problem constants
#define BB 64
#define VV 2000
#define DD 16
#define CI 64
#define CO 64

// ---- ws layout ----
// dword offsets (fp32 region)
#define WS_INV_DW   0
#define WS_Z_DW     1024                    // float2[16][4096]
#define WS_BIAS_DW  132096                  // fp32 [2000][128]  (idx = 2*o+half)
// byte offsets (bf16 regions), all 16B-aligned
#define WS_NE_B     1552384UL               // bf16 [2048][64]  (hi/lo split ne)
#define WS_RHS_B    1814528UL               // bf16 [16384][64] compact RHS
#define WS_U_B      4960256UL               // bf16 [2000][3][64][64] compact U
#define WS_W_B      54112256UL              // bf16 [2000][4][64][64] compact W
// ZP (k_z partials, 8.4 MB) and NP (norm1 partials, 51 KB) alias the U region:
// written by k_front, consumed by k_mid, then overwritten by k_u. This keeps
// them OUT of the W region so k_mid can run zred+norm2+wgemm concurrently.
#define WS_ZP_DW    (WS_U_B / 4)            // 1240064
#define WS_NP_DW    (WS_ZP_DW + 2097152)    // 25 blocks x 512 floats

typedef __attribute__((ext_vector_type(8))) short short8;
typedef __attribute__((ext_vector_type(4))) float f32x4;

__device__ __forceinline__ uint32_t f2bf(float f) {
  uint32_t u = __float_as_uint(f);
  return (u + 0x7FFFu + ((u >> 16) & 1u)) >> 16;   // RNE
}

// Direct global->LDS DMA, 16B per lane. LDS dest = wave-uniform base +
// lane*16; global src is per-lane. No VGPR round trip, no scratch.
__device__ __forceinline__ void gload_lds16(const void* g, void* l) {
  __builtin_amdgcn_global_load_lds(
      (const __attribute__((address_space(1))) uint32_t*)g,
      (__attribute__((address_space(3))) uint32_t*)l, 16, 0, 0);
}

// ---------------------------------------------------------------------------
// Component bodies (device-inline), fused into k_front / k_mid by blockIdx
// range. All components use 256-thread blocks. Dependencies:
//   k_front: {z, ne, rhs, norm1-partials, bias}   (mutually independent)
//   k_mid:   {wgemm, zred, norm2}                 (all need only k_front)
//   k_u:     needs Z + INV (k_mid)
//   k_final: needs W (k_mid) + U (k_u) + bias (k_front)
// ---------------------------------------------------------------------------

// z: Z partials. 1024 virtual blocks = (b:64)x(chunk:16).
// R2: wave-uniform v-range (scalar ne loads), x tile staged in LDS.
// R5: staging via global_load_lds — R5 counters showed the old float4 rx[8]
// staging lived in SCRATCH (VGPR=44 can't hold it; WRITE_SIZE excess of
// ~32 MB == 1024 blk x 256 thr x 128 B), adding a full HBM round trip.
__device__ __forceinline__ void body_z(int bz, int t,
    const float* __restrict__ x, const float* __restrict__ ne_re,
    const float* __restrict__ ne_im, float* __restrict__ ws) {
  int b = bz >> 4, c = bz & 15;
  int lane = t & 63;
  int w = __builtin_amdgcn_readfirstlane(t >> 6);   // wave-uniform in SGPR
  __shared__ __align__(16) float smem[8192];        // 32 KB: x-tile, then sred

  int vbase = c * 125;

  // stage x[b, vbase..vbase+125, :] = 32000 B contiguous into LDS via DMA.
  // chunk idx = p*256 + t; LDS dest base (p*256 + w*64)*16B, lane*16B offset.
  {
    const float4* xg = (const float4*)(x + ((size_t)b * VV + vbase) * CI);
    int wb = t & 192;                               // w*64, uniform per wave
    #pragma unroll
    for (int p = 0; p < 8; ++p) {
      int idx = p * 256 + t;
      if (idx < 2000)
        gload_lds16(xg + idx, &smem[(p * 256 + wb) * 4]);
    }
  }
  __syncthreads();                                  // compiler drains vmcnt

  float zr[DD], zi[DD];
  #pragma unroll
  for (int d = 0; d < DD; ++d) { zr[d] = 0.f; zi[d] = 0.f; }

  int lv0 = (w * 125) >> 2;                         // uniform bounds (SGPR)
  int lv1 = ((w + 1) * 125) >> 2;
  #pragma unroll 4
  for (int lv = lv0; lv < lv1; ++lv) {
    float xv = smem[lv * 64 + lane];                // stride-1: conflict-free
    int v = vbase + lv;                             // uniform -> s_load ne
    #pragma unroll
    for (int d = 0; d < DD; ++d) {
      zr[d] += ne_re[v*DD + d] * xv;
      zi[d] -= ne_im[v*DD + d] * xv;
    }
  }
  __syncthreads();                                  // all waves done with x-tile

  #pragma unroll
  for (int d = 0; d < DD; ++d) {
    smem[w*2048 + d*128 + lane*2 + 0] = zr[d];
    smem[w*2048 + d*128 + lane*2 + 1] = zi[d];
  }
  __syncthreads();
  float* ZP = ws + WS_ZP_DW;
  #pragma unroll
  for (int k = 0; k < 8; ++k) {
    int j = t + k*256;
    float s = smem[j] + smem[2048 + j] + smem[4096 + j] + smem[6144 + j];
    int d = j >> 7, r = j & 127;
    ZP[(size_t)c*131072 + d*8192 + b*128 + r] = s;
  }
}

// ne: NE[u][col] bf16, col = h*32 + d*2 + p; h=0: bf16(ne), h=1: bf16(ne - hi)
__device__ __forceinline__ void body_ne(int bx, int t,
    const float* __restrict__ ne_re, const float* __restrict__ ne_im,
    float* __restrict__ ws) {
  int gid = bx * 256 + t;                     // 512 blocks -> 131072
  int u = gid >> 6, col = gid & 63;
  int h = col >> 5, kk = col & 31, d = kk >> 1, p = kk & 1;
  float v = 0.f;
  if (u < VV) v = p ? ne_im[u*DD + d] : ne_re[u*DD + d];
  uint32_t hi = f2bf(v);
  uint32_t ov = h ? f2bf(v - __uint_as_float(hi << 16)) : hi;
  ((uint16_t*)((char*)ws + WS_NE_B))[gid] = (uint16_t)ov;
}

// rhs: compact RHS[n'][k], n' = c*4096 + o*64 + s*8 + e (granule-swizzle baked)
__device__ __forceinline__ void body_rhs(int bx, int t,
    const float* __restrict__ w_re, const float* __restrict__ w_im,
    float* __restrict__ ws) {
  int c = bx >> 4, ig4 = bx & 15;
  int o = t & 63, il = t >> 6;
  int i = ig4*4 + il;
  int cb = c >> 1;                     // 0: wA = w0-w2, 1: wB = w1+2w2
  int imf = c & 1;                     // odd comp: (Im, Re); even: (Re, -Im)

  uint32_t row32[16];
  #pragma unroll
  for (int d = 0; d < DD; ++d) {
    int b0 = (d*192 + i)*64 + o;       // w[d,kc,i,o]: d stride 12288, kc 4096
    float vre, vim;
    if (cb == 0) {
      vre = w_re[b0] - w_re[b0 + 8192];
      vim = w_im[b0] - w_im[b0 + 8192];
    } else {
      vre = w_re[b0 + 4096] + 2.f*w_re[b0 + 8192];
      vim = w_im[b0 + 4096] + 2.f*w_im[b0 + 8192];
    }
    float q0 = imf ? vim : vre;
    float q1 = imf ? vre : -vim;
    row32[d] = f2bf(q0) | (f2bf(q1) << 16);
  }
  int s = ((i >> 3) ^ (o & 7)) & 7;
  int n = c*4096 + o*64 + s*8 + (i & 7);
  uint4* dst = (uint4*)((uint16_t*)((char*)ws + WS_RHS_B) + (size_t)n*64);
  #pragma unroll
  for (int j = 0; j < 4; ++j) {
    uint4 qv = make_uint4(row32[4*j], row32[4*j+1], row32[4*j+2], row32[4*j+3]);
    dst[j]     = qv;   // h=0
    dst[j + 4] = qv;   // h=1 duplicate (hi/lo ne split reconstructs fp32)
  }
}

// norm1: partial Gram, 25 virtual blocks x 80 v. Writes per-block partials to
// NP (no atomics, no pre-zeroing needed -> k_zero deleted).
__device__ __forceinline__ void body_norm1(int bx, int t,
    const float* __restrict__ ne_re, const float* __restrict__ ne_im,
    float* __restrict__ ws) {
  int d = t >> 4, e = t & 15;
  int v0 = bx * 80;
  float gr = 0.f, gi = 0.f;
  for (int v = v0; v < v0 + 80; ++v) {
    float ar = ne_re[v*DD + d], ai = ne_im[v*DD + d];
    float br = ne_re[v*DD + e], bi = ne_im[v*DD + e];
    gr += ar*br + ai*bi;
    gi += ar*bi - ai*br;
  }
  float* NP = ws + WS_NP_DW;
  NP[bx*512 + 2*t]     = gr;
  NP[bx*512 + 2*t + 1] = gi;
}

// bias: bias2[u][2*o+half] fp32 (interleaved so k_final stores are linear)
__device__ __forceinline__ void body_bias(int bx, int t,
    const float* __restrict__ ne_re, const float* __restrict__ ne_im,
    const float* __restrict__ b_re, const float* __restrict__ b_im,
    float* __restrict__ ws) {
  int gid = bx * 256 + t;                     // 1000 blocks -> 256000
  int u = gid >> 7, idx = gid & 127;
  int o = idx >> 1, half = idx & 1;
  float acc = 0.f;
  #pragma unroll
  for (int d = 0; d < DD; ++d) {
    float nr = ne_re[u*DD + d], ni = ne_im[u*DD + d];
    float pr = b_re[d*CO + o],  pi = b_im[d*CO + o];
    acc += half ? (nr*pi + ni*pr) : (nr*pr - ni*pi);
  }
  ws[WS_BIAS_DW + gid] = acc;
}

// wgemm: W GEMM -> compact Wc[u][16384].
__device__ __forceinline__ void body_wgemm(int bx, int t, float* __restrict__ ws) {
  const uint16_t* NE  = (const uint16_t*)((char*)ws + WS_NE_B);
  const uint16_t* RHS = (const uint16_t*)((char*)ws + WS_RHS_B);
  uint32_t*       W   = (uint32_t*)((char*)ws + WS_W_B);
  int ut = bx & 31, nc = bx >> 5;
  int w = t >> 6, lane = t & 63;
  int n16 = lane & 15, quad = lane >> 4;
  short8 a[4][2];
  #pragma unroll
  for (int m = 0; m < 4; ++m) {
    int u = ut*64 + m*16 + n16;
    a[m][0] = *(const short8*)(NE + u*64 + quad*8);
    a[m][1] = *(const short8*)(NE + u*64 + 32 + quad*8);
  }
  int nbase = nc*1024 + w*256;
  #pragma unroll 2
  for (int pt = 0; pt < 8; ++pt) {
    int nb = nbase + pt*32;
    const uint16_t* r0 = RHS + (size_t)(nb + 2*n16 + 0)*64 + quad*8;
    const uint16_t* r1 = RHS + (size_t)(nb + 2*n16 + 1)*64 + quad*8;
    short8 b00 = *(const short8*)r0;
    short8 b01 = *(const short8*)(r0 + 32);
    short8 b10 = *(const short8*)r1;
    short8 b11 = *(const short8*)(r1 + 32);
    #pragma unroll
    for (int m = 0; m < 4; ++m) {
      f32x4 acc0 = (f32x4){0.f,0.f,0.f,0.f};
      f32x4 acc1 = (f32x4){0.f,0.f,0.f,0.f};
      acc0 = __builtin_amdgcn_mfma_f32_16x16x32_bf16(a[m][0], b00, acc0, 0, 0, 0);
      acc0 = __builtin_amdgcn_mfma_f32_16x16x32_bf16(a[m][1], b01, acc0, 0, 0, 0);
      acc1 = __builtin_amdgcn_mfma_f32_16x16x32_bf16(a[m][0], b10, acc1, 0, 0, 0);
      acc1 = __builtin_amdgcn_mfma_f32_16x16x32_bf16(a[m][1], b11, acc1, 0, 0, 0);
      #pragma unroll
      for (int r = 0; r < 4; ++r) {
        int u = ut*64 + m*16 + quad*4 + r;
        if (u < VV) {
          uint32_t pk = f2bf(acc0[r]) | (f2bf(acc1[r]) << 16);
          W[(size_t)u*8192 + (nb >> 1) + n16] = pk;
        }
      }
    }
  }
}

// zred: Z = sum over 16 chunks of ZP. 256 virtual blocks.
__device__ __forceinline__ void body_zred(int bx, int t, float* __restrict__ ws) {
  int g = bx * 256 + t;
  const float2* ZP2 = (const float2*)(ws + WS_ZP_DW);
  float2 acc = make_float2(0.f, 0.f);
  #pragma unroll
  for (int c = 0; c < 16; ++c) {
    float2 v = ZP2[(size_t)c*65536 + g];
    acc.x += v.x; acc.y += v.y;
  }
  ((float2*)(ws + WS_Z_DW))[g] = acc;
}

// norm2: reduce NP partials -> INV. 1 virtual block.
__device__ __forceinline__ void body_norm2(int t, float* __restrict__ ws) {
  const float* NP = ws + WS_NP_DW;
  float gr = 0.f, gi = 0.f;
  #pragma unroll
  for (int p = 0; p < 25; ++p) {
    gr += NP[p*512 + 2*t];
    gi += NP[p*512 + 2*t + 1];
  }
  __shared__ float red[256];
  red[t] = gr*gr + gi*gi;
  __syncthreads();
  for (int k = 128; k > 0; k >>= 1) {
    if (t < k) red[t] += red[t + k];
    __syncthreads();
  }
  if (t == 0) ws[WS_INV_DW] = 1.0f / sqrtf(red[0]);
}

// ---------------------------------------------------------------------------
// Fused dispatchers
// ---------------------------------------------------------------------------

// k_front: 2625 blocks. z [0,1024) | ne [1024,1536) | rhs [1536,1600) |
//          norm1 [1600,1625) | bias [1625,2625). z first: it's the long pole.
__global__ void __launch_bounds__(256, 4)
k_front(const float* __restrict__ x, const float* __restrict__ ne_re,
        const float* __restrict__ ne_im, const float* __restrict__ w_re,
        const float* __restrict__ w_im, const float* __restrict__ b_re,
        const float* __restrict__ b_im, float* __restrict__ ws) {
  int bx = blockIdx.x, t = threadIdx.x;
  if (bx < 1024) {
    body_z(bx, t, x, ne_re, ne_im, ws);
  } else if (bx < 1536) {
    body_ne(bx - 1024, t, ne_re, ne_im, ws);
  } else if (bx < 1600) {
    body_rhs(bx - 1536, t, w_re, w_im, ws);
  } else if (bx < 1625) {
    body_norm1(bx - 1600, t, ne_re, ne_im, ws);
  } else {
    body_bias(bx - 1625, t, ne_re, ne_im, b_re, b_im, ws);
  }
}

// k_mid: 769 blocks. wgemm [0,512) | zred [512,768) | norm2 768.
// ZP/NP live in the U region (not W), so wgemm's W writes don't race zred.
__global__ void __launch_bounds__(256, 4)
k_mid(float* __restrict__ ws) {
  int bx = blockIdx.x, t = threadIdx.x;
  if (bx < 512) {
    body_wgemm(bx, t, ws);
  } else if (bx < 768) {
    body_zred(bx - 512, t, ws);
  } else {
    body_norm2(t, ws);
  }
}

// K7: compact U[u][3][64][64] (c: x, yr, yi; swizzle baked), LDS-staged stores.
// grid (125 ug, 16 by), block 256 = 4 b x 64 i, 16 u per block.
// R1: prefetch x16, Z loads behind, drain x->LDS, unrolled y loop.
// R5: pin the 16 prefetched x values live in VGPRs via empty asm — R1's
// VGPR_Count=48 proved the compiler re-serialized the loads (48 regs can't
// hold xv[16]+zr/zi[32]); the asm forces one latency exposure, not 16.
__global__ void __launch_bounds__(256, 4)
k_u(const float* __restrict__ x, const float* __restrict__ ne_re,
    const float* __restrict__ ne_im, float* __restrict__ ws) {
  int ug = blockIdx.x, by = blockIdx.y;
  int t = threadIdx.x, q = t >> 6, i = t & 63;
  int b = by*4 + q;
  float invn = ws[WS_INV_DW];

  // (1) prefetch all 16 x values: independent coalesced 4B loads
  float xv[16];
  {
    const float* xp = x + ((size_t)b*VV + (size_t)ug*16)*CI + i;
    #pragma unroll
    for (int ul = 0; ul < 16; ++ul) xv[ul] = xp[(size_t)ul*CI];
    #pragma unroll
    for (int ul = 0; ul < 16; ++ul) asm volatile("" : "+v"(xv[ul]));
  }

  // (2) Z loads (16 x 8B, cache-resident) — land while x is in flight
  const float* Z = ws + WS_Z_DW;
  float zr[DD], zi[DD];
  #pragma unroll
  for (int d = 0; d < DD; ++d) {
    const float* zp = Z + (size_t)(d*4096 + b*64 + i) * 2;
    zr[d] = zp[0]; zi[d] = zp[1];
  }

  __shared__ uint16_t sStage[192 * 64];       // rr = ul*12 + c*4 + q
  int bkey = b & 7;
  int pos = (((i >> 3) ^ bkey) & 7)*8 + (i & 7);

  // (3) drain x -> LDS (frees xv registers before the FMA-heavy loop)
  #pragma unroll
  for (int ul = 0; ul < 16; ++ul)
    sStage[(ul*12 + 0 + q)*64 + pos] = (uint16_t)f2bf(xv[ul]);

  // (4) y compute, fully unrolled, split accumulators
  #pragma unroll
  for (int ul = 0; ul < 16; ++ul) {
    int u = ug*16 + ul;
    float yra = 0.f, yrb = 0.f, yia = 0.f, yib = 0.f;
    #pragma unroll
    for (int d = 0; d < DD; ++d) {
      float nr = ne_re[u*DD + d], ni = ne_im[u*DD + d];
      yra += nr*zr[d]; yrb += ni*zi[d];
      yia += nr*zi[d]; yib += ni*zr[d];
    }
    float yr = yra - yrb, yi = yia + yib;
    sStage[(ul*12 + 4 + q)*64 + pos] = (uint16_t)f2bf(yr * invn);
    sStage[(ul*12 + 8 + q)*64 + pos] = (uint16_t)f2bf(yi * invn);
  }
  __syncthreads();
  // flush: 192 rows x 128B, 32 rows per pass (8 lanes/row), 6 passes
  uint16_t* U = (uint16_t*)((char*)ws + WS_U_B);
  const uint4* sv = (const uint4*)sStage;
  #pragma unroll
  for (int pass = 0; pass < 6; ++pass) {
    int rr = pass*32 + (t >> 3), l8 = t & 7;
    int ul = rr / 12, rem = rr - ul*12;
    int c = rem >> 2, qq = rem & 3;
    uint4 v = sv[rr*8 + l8];
    *(uint4*)(U + (size_t)(ug*16 + ul)*12288 + c*4096 + (by*4 + qq)*64 + l8*8) = v;
  }
}

// K8: per-node MFMA from compact W,U. LDS pitch 80 elems (160B) -> <=2-way
// bank conflicts. Out stores: wave columns = (8 o)x(re,im) interleaved ->
// 16 consecutive dwords = 64B lines.
#define LP 80           // LDS row pitch (elems)
#define CSTRIDE 5120    // 64*LP: comp stride (elems)
__global__ void __launch_bounds__(512, 2)
k_final(const float* __restrict__ ws, float* __restrict__ out) {
  int u = blockIdx.x, t = threadIdx.x;
  __shared__ __align__(16) uint16_t sW[4 * CSTRIDE];   // 40960B
  __shared__ __align__(16) uint16_t sU[3 * CSTRIDE];   // 30720B
  const uint4* Wg = (const uint4*)((const char*)ws + WS_W_B + (size_t)u*32768);
  const uint4* Ug = (const uint4*)((const char*)ws + WS_U_B + (size_t)u*24576);
  #pragma unroll
  for (int j = 0; j < 4; ++j) {
    int idx = j*512 + t;                       // 2048 chunks of 16B
    int row = idx >> 3, col = idx & 7;
    *(uint4*)&sW[row*LP + col*8] = Wg[idx];
  }
  #pragma unroll
  for (int j = 0; j < 3; ++j) {
    int idx = j*512 + t;                       // 1536 chunks
    int row = idx >> 3, col = idx & 7;
    *(uint4*)&sU[row*LP + col*8] = Ug[idx];
  }
  __syncthreads();

  int w = t >> 6, lane = t & 63;
  int n16 = lane & 15, quad = lane >> 4;
  int o = w*8 + (n16 >> 1), half = n16 & 1;
  int okey = o & 7;
  uint32_t sgnmask = half ? 0u : 0x80008000u;  // negate Bi for re-half at cb=2
  f32x4 acc[4];
  #pragma unroll
  for (int m = 0; m < 4; ++m) acc[m] = (f32x4){0.f,0.f,0.f,0.f};

  #pragma unroll
  for (int ks = 0; ks < 6; ++ks) {
    int cb = ks >> 1;                          // 0,0,1,1,2,2
    int i8 = (ks & 1)*4 + quad;                // logical granule & 7
    int c  = (cb == 0) ? half : ((cb == 1) ? 2 + half : 3 - half);
    int slot = (i8 ^ okey) & 7;
    short8 bfrag = *(const short8*)&sW[c*CSTRIDE + o*LP + slot*8];
    if (cb == 2) {
      uint32_t* bu = (uint32_t*)&bfrag;
      #pragma unroll
      for (int jj = 0; jj < 4; ++jj) bu[jj] ^= sgnmask;
    }
    #pragma unroll
    for (int m = 0; m < 4; ++m) {
      int b = m*16 + n16;
      int aslot = (i8 ^ (b & 7)) & 7;
      short8 afrag = *(const short8*)&sU[cb*CSTRIDE + b*LP + aslot*8];
      acc[m] = __builtin_amdgcn_mfma_f32_16x16x32_bf16(afrag, bfrag, acc[m], 0, 0, 0);
    }
  }

  float bias = ws[WS_BIAS_DW + u*128 + w*16 + n16];
  #pragma unroll
  for (int m = 0; m < 4; ++m) {
    #pragma unroll
    for (int r = 0; r < 4; ++r) {
      int b = m*16 + quad*4 + r;
      out[((size_t)b*VV + u)*128 + w*16 + n16] = acc[m][r] + bias;
    }
  }
}

// ---------------------------------------------------------------------------
extern "C" void kernel_launch(void* const* d_in, const int* in_sizes, int n_in,
                              void* d_out, int out_size, void* d_ws, size_t ws_size,
                              hipStream_t stream) {
  (void)in_sizes; (void)n_in; (void)out_size; (void)ws_size;
  const float* x     = (const float*)d_in[0];
  const float* ne_re = (const float*)d_in[1];
  const float* ne_im = (const float*)d_in[2];
  const float* w_re  = (const float*)d_in[3];
  const float* w_im  = (const float*)d_in[4];
  const float* b_re  = (const float*)d_in[5];
  const float* b_im  = (const float*)d_in[6];
  float* out = (float*)d_out;
  float* ws  = (float*)d_ws;

  k_front<<<dim3(2625),    dim3(256), 0, stream>>>(x, ne_re, ne_im, w_re, w_im,
                                                   b_re, b_im, ws);
  k_mid  <<<dim3(769),     dim3(256), 0, stream>>>(ws);
  k_u    <<<dim3(125, 16), dim3(256), 0, stream>>>(ws == nullptr ? x : x, ne_re, ne_im, ws);
  k_final<<<dim3(VV),      dim3(512), 0, stream>>>(ws, out);
}

// Round 8
// 181.540 us; speedup vs baseline: 1.3313x; 1.0395x over previous
//
#include <hip/hip_runtime.h>
#include <stdint.h>

// Problem constants
#define BB 64
#define VV 2000
#define DD 16
#define CI 64
#define CO 64

// ---- ws layout ----
// dword offsets (fp32 region)
#define WS_INV_DW   0
#define WS_Z_DW     1024                    // float2[16][4096]
#define WS_BIAS_DW  132096                  // fp32 [2000][128]  (idx = 2*o+half)
// byte offsets (bf16 regions), all 16B-aligned
#define WS_NE_B     1552384UL               // bf16 [2048][64]  (hi/lo split ne)
#define WS_RHS_B    1814528UL               // bf16 [16384][64] compact RHS
#define WS_U_B      4960256UL               // bf16 [2000][3][64][64] compact U
#define WS_W_B      54112256UL               // bf16 [2000][4][64][64] compact W
// ZP (k_z partials, 8.4 MB) and NP (norm1 partials, 205 KB) alias the U region:
// written by k_front, consumed by k_mid, then overwritten by k_u.
#define WS_ZP_DW    (WS_U_B / 4)            // 1240064
#define WS_NP_DW    (WS_ZP_DW + 2097152)    // 100 blocks x 512 floats

typedef __attribute__((ext_vector_type(8))) short short8;
typedef __attribute__((ext_vector_type(4))) float f32x4;

__device__ __forceinline__ uint32_t f2bf(float f) {
  uint32_t u = __float_as_uint(f);
  return (u + 0x7FFFu + ((u >> 16) & 1u)) >> 16;   // RNE
}

// Direct global->LDS DMA, 16B per lane. LDS dest = wave-uniform base +
// lane*16; global src is per-lane. No VGPR round trip, no scratch.
__device__ __forceinline__ void gload_lds16(const void* g, void* l) {
  __builtin_amdgcn_global_load_lds(
      (const __attribute__((address_space(1))) uint32_t*)g,
      (__attribute__((address_space(3))) uint32_t*)l, 16, 0, 0);
}

// ---------------------------------------------------------------------------
// Component bodies, fused into k_front / k_mid by blockIdx range.
//   k_front: {z, rhs, norm1, bias, ne}   (mutually independent)
//   k_mid:   {wgemm, zred, norm2}        (all need only k_front)
//   k_u:     needs Z + INV (k_mid)
//   k_final: needs W (k_mid) + U (k_u) + bias (k_front)
// R7: rhs widened 64->256 blocks (4-way d-split; was a 16-CU straggler
// reading 25 MB), norm1 widened 25->100 blocks (was an 80-deep latency
// chain on 25 CUs); dispatch order = longest-per-block first so the wide
// short phases backfill CUs as z retires.
// ---------------------------------------------------------------------------

// z: Z partials. 1024 virtual blocks = (b:64)x(chunk:16).
// R2: wave-uniform v-range (scalar ne loads), x tile staged in LDS.
// R5: staging via global_load_lds (old reg-staging lived in scratch:
// WRITE_SIZE excess ~32 MB == 1024 blk x 256 thr x 128 B).
__device__ __forceinline__ void body_z(int bz, int t,
    const float* __restrict__ x, const float* __restrict__ ne_re,
    const float* __restrict__ ne_im, float* __restrict__ ws) {
  int b = bz >> 4, c = bz & 15;
  int lane = t & 63;
  int w = __builtin_amdgcn_readfirstlane(t >> 6);   // wave-uniform in SGPR
  __shared__ __align__(16) float smem[8192];        // 32 KB: x-tile, then sred

  int vbase = c * 125;

  // stage x[b, vbase..vbase+125, :] = 32000 B contiguous into LDS via DMA.
  {
    const float4* xg = (const float4*)(x + ((size_t)b * VV + vbase) * CI);
    int wb = t & 192;                               // w*64, uniform per wave
    #pragma unroll
    for (int p = 0; p < 8; ++p) {
      int idx = p * 256 + t;
      if (idx < 2000)
        gload_lds16(xg + idx, &smem[(p * 256 + wb) * 4]);
    }
  }
  __syncthreads();                                  // compiler drains vmcnt

  float zr[DD], zi[DD];
  #pragma unroll
  for (int d = 0; d < DD; ++d) { zr[d] = 0.f; zi[d] = 0.f; }

  int lv0 = (w * 125) >> 2;                         // uniform bounds (SGPR)
  int lv1 = ((w + 1) * 125) >> 2;
  #pragma unroll 4
  for (int lv = lv0; lv < lv1; ++lv) {
    float xv = smem[lv * 64 + lane];                // stride-1: conflict-free
    int v = vbase + lv;                             // uniform -> s_load ne
    #pragma unroll
    for (int d = 0; d < DD; ++d) {
      zr[d] += ne_re[v*DD + d] * xv;
      zi[d] -= ne_im[v*DD + d] * xv;
    }
  }
  __syncthreads();                                  // all waves done with x-tile

  #pragma unroll
  for (int d = 0; d < DD; ++d) {
    smem[w*2048 + d*128 + lane*2 + 0] = zr[d];
    smem[w*2048 + d*128 + lane*2 + 1] = zi[d];
  }
  __syncthreads();
  float* ZP = ws + WS_ZP_DW;
  #pragma unroll
  for (int k = 0; k < 8; ++k) {
    int j = t + k*256;
    float s = smem[j] + smem[2048 + j] + smem[4096 + j] + smem[6144 + j];
    int d = j >> 7, r = j & 127;
    ZP[(size_t)c*131072 + d*8192 + b*128 + r] = s;
  }
}

// ne: NE[u][col] bf16, col = h*32 + d*2 + p; h=0: bf16(ne), h=1: bf16(ne - hi)
__device__ __forceinline__ void body_ne(int bx, int t,
    const float* __restrict__ ne_re, const float* __restrict__ ne_im,
    float* __restrict__ ws) {
  int gid = bx * 256 + t;                     // 512 blocks -> 131072
  int u = gid >> 6, col = gid & 63;
  int h = col >> 5, kk = col & 31, d = kk >> 1, p = kk & 1;
  float v = 0.f;
  if (u < VV) v = p ? ne_im[u*DD + d] : ne_re[u*DD + d];
  uint32_t hi = f2bf(v);
  uint32_t ov = h ? f2bf(v - __uint_as_float(hi << 16)) : hi;
  ((uint16_t*)((char*)ws + WS_NE_B))[gid] = (uint16_t)ov;
}

// rhs: compact RHS[n'][k]. R7: 256 blocks = (c:4)x(ig4:16)x(dq:4); each block
// handles d = dq*4..dq*4+3 and writes its own disjoint uint4 pair (cols
// 8dq..8dq+7 in both h-halves) of each row.
__device__ __forceinline__ void body_rhs(int bx, int t,
    const float* __restrict__ w_re, const float* __restrict__ w_im,
    float* __restrict__ ws) {
  int c = bx >> 6, sub = bx & 63;
  int ig4 = sub & 15, dq = sub >> 4;
  int o = t & 63, il = t >> 6;
  int i = ig4*4 + il;
  int cb = c >> 1;                     // 0: wA = w0-w2, 1: wB = w1+2w2
  int imf = c & 1;                     // odd comp: (Im, Re); even: (Re, -Im)

  uint32_t row32[4];
  #pragma unroll
  for (int d4 = 0; d4 < 4; ++d4) {
    int d = dq*4 + d4;
    int b0 = (d*192 + i)*64 + o;       // w[d,kc,i,o]: d stride 12288, kc 4096
    float vre, vim;
    if (cb == 0) {
      vre = w_re[b0] - w_re[b0 + 8192];
      vim = w_im[b0] - w_im[b0 + 8192];
    } else {
      vre = w_re[b0 + 4096] + 2.f*w_re[b0 + 8192];
      vim = w_im[b0 + 4096] + 2.f*w_im[b0 + 8192];
    }
    float q0 = imf ? vim : vre;
    float q1 = imf ? vre : -vim;
    row32[d4] = f2bf(q0) | (f2bf(q1) << 16);
  }
  int s = ((i >> 3) ^ (o & 7)) & 7;
  int n = c*4096 + o*64 + s*8 + (i & 7);
  uint4* dst = (uint4*)((uint16_t*)((char*)ws + WS_RHS_B) + (size_t)n*64);
  uint4 qv = make_uint4(row32[0], row32[1], row32[2], row32[3]);
  dst[dq]     = qv;   // h=0
  dst[dq + 4] = qv;   // h=1 duplicate (hi/lo ne split reconstructs fp32)
}

// norm1: partial Gram. R7: 100 virtual blocks x 20 v (was 25x80: a 25-CU
// 80-deep latency-chain straggler). Per-block partials to NP, no atomics.
__device__ __forceinline__ void body_norm1(int bx, int t,
    const float* __restrict__ ne_re, const float* __restrict__ ne_im,
    float* __restrict__ ws) {
  int d = t >> 4, e = t & 15;
  int v0 = bx * 20;
  float gr = 0.f, gi = 0.f;
  #pragma unroll 4
  for (int v = v0; v < v0 + 20; ++v) {
    float ar = ne_re[v*DD + d], ai = ne_im[v*DD + d];
    float br = ne_re[v*DD + e], bi = ne_im[v*DD + e];
    gr += ar*br + ai*bi;
    gi += ar*bi - ai*br;
  }
  float* NP = ws + WS_NP_DW;
  NP[bx*512 + 2*t]     = gr;
  NP[bx*512 + 2*t + 1] = gi;
}

// bias: bias2[u][2*o+half] fp32 (interleaved so k_final stores are linear)
__device__ __forceinline__ void body_bias(int bx, int t,
    const float* __restrict__ ne_re, const float* __restrict__ ne_im,
    const float* __restrict__ b_re, const float* __restrict__ b_im,
    float* __restrict__ ws) {
  int gid = bx * 256 + t;                     // 1000 blocks -> 256000
  int u = gid >> 7, idx = gid & 127;
  int o = idx >> 1, half = idx & 1;
  float acc = 0.f;
  #pragma unroll
  for (int d = 0; d < DD; ++d) {
    float nr = ne_re[u*DD + d], ni = ne_im[u*DD + d];
    float pr = b_re[d*CO + o],  pi = b_im[d*CO + o];
    acc += half ? (nr*pi + ni*pr) : (nr*pr - ni*pi);
  }
  ws[WS_BIAS_DW + gid] = acc;
}

// wgemm: W GEMM -> compact Wc[u][16384].
__device__ __forceinline__ void body_wgemm(int bx, int t, float* __restrict__ ws) {
  const uint16_t* NE  = (const uint16_t*)((char*)ws + WS_NE_B);
  const uint16_t* RHS = (const uint16_t*)((char*)ws + WS_RHS_B);
  uint32_t*       W   = (uint32_t*)((char*)ws + WS_W_B);
  int ut = bx & 31, nc = bx >> 5;
  int w = t >> 6, lane = t & 63;
  int n16 = lane & 15, quad = lane >> 4;
  short8 a[4][2];
  #pragma unroll
  for (int m = 0; m < 4; ++m) {
    int u = ut*64 + m*16 + n16;
    a[m][0] = *(const short8*)(NE + u*64 + quad*8);
    a[m][1] = *(const short8*)(NE + u*64 + 32 + quad*8);
  }
  int nbase = nc*1024 + w*256;
  #pragma unroll 2
  for (int pt = 0; pt < 8; ++pt) {
    int nb = nbase + pt*32;
    const uint16_t* r0 = RHS + (size_t)(nb + 2*n16 + 0)*64 + quad*8;
    const uint16_t* r1 = RHS + (size_t)(nb + 2*n16 + 1)*64 + quad*8;
    short8 b00 = *(const short8*)r0;
    short8 b01 = *(const short8*)(r0 + 32);
    short8 b10 = *(const short8*)r1;
    short8 b11 = *(const short8*)(r1 + 32);
    #pragma unroll
    for (int m = 0; m < 4; ++m) {
      f32x4 acc0 = (f32x4){0.f,0.f,0.f,0.f};
      f32x4 acc1 = (f32x4){0.f,0.f,0.f,0.f};
      acc0 = __builtin_amdgcn_mfma_f32_16x16x32_bf16(a[m][0], b00, acc0, 0, 0, 0);
      acc0 = __builtin_amdgcn_mfma_f32_16x16x32_bf16(a[m][1], b01, acc0, 0, 0, 0);
      acc1 = __builtin_amdgcn_mfma_f32_16x16x32_bf16(a[m][0], b10, acc1, 0, 0, 0);
      acc1 = __builtin_amdgcn_mfma_f32_16x16x32_bf16(a[m][1], b11, acc1, 0, 0, 0);
      #pragma unroll
      for (int r = 0; r < 4; ++r) {
        int u = ut*64 + m*16 + quad*4 + r;
        if (u < VV) {
          uint32_t pk = f2bf(acc0[r]) | (f2bf(acc1[r]) << 16);
          W[(size_t)u*8192 + (nb >> 1) + n16] = pk;
        }
      }
    }
  }
}

// zred: Z = sum over 16 chunks of ZP. 256 virtual blocks.
__device__ __forceinline__ void body_zred(int bx, int t, float* __restrict__ ws) {
  int g = bx * 256 + t;
  const float2* ZP2 = (const float2*)(ws + WS_ZP_DW);
  float2 acc = make_float2(0.f, 0.f);
  #pragma unroll
  for (int c = 0; c < 16; ++c) {
    float2 v = ZP2[(size_t)c*65536 + g];
    acc.x += v.x; acc.y += v.y;
  }
  ((float2*)(ws + WS_Z_DW))[g] = acc;
}

// norm2: reduce NP partials -> INV. 1 virtual block. R7: 100 partials.
__device__ __forceinline__ void body_norm2(int t, float* __restrict__ ws) {
  const float* NP = ws + WS_NP_DW;
  float gr = 0.f, gi = 0.f;
  #pragma unroll
  for (int p = 0; p < 100; ++p) {
    gr += NP[p*512 + 2*t];
    gi += NP[p*512 + 2*t + 1];
  }
  __shared__ float red[256];
  red[t] = gr*gr + gi*gi;
  __syncthreads();
  for (int k = 128; k > 0; k >>= 1) {
    if (t < k) red[t] += red[t + k];
    __syncthreads();
  }
  if (t == 0) ws[WS_INV_DW] = 1.0f / sqrtf(red[0]);
}

// ---------------------------------------------------------------------------
// Fused dispatchers
// ---------------------------------------------------------------------------

// k_front: 2892 blocks, longest-per-block first:
//   z [0,1024) | rhs [1024,1280) | norm1 [1280,1380) |
//   bias [1380,2380) | ne [2380,2892)
__global__ void __launch_bounds__(256, 4)
k_front(const float* __restrict__ x, const float* __restrict__ ne_re,
        const float* __restrict__ ne_im, const float* __restrict__ w_re,
        const float* __restrict__ w_im, const float* __restrict__ b_re,
        const float* __restrict__ b_im, float* __restrict__ ws) {
  int bx = blockIdx.x, t = threadIdx.x;
  if (bx < 1024) {
    body_z(bx, t, x, ne_re, ne_im, ws);
  } else if (bx < 1280) {
    body_rhs(bx - 1024, t, w_re, w_im, ws);
  } else if (bx < 1380) {
    body_norm1(bx - 1280, t, ne_re, ne_im, ws);
  } else if (bx < 2380) {
    body_bias(bx - 1380, t, ne_re, ne_im, b_re, b_im, ws);
  } else {
    body_ne(bx - 2380, t, ne_re, ne_im, ws);
  }
}

// k_mid: 769 blocks. wgemm [0,512) | zred [512,768) | norm2 768.
// ZP/NP live in the U region (not W), so wgemm's W writes don't race zred.
__global__ void __launch_bounds__(256, 4)
k_mid(float* __restrict__ ws) {
  int bx = blockIdx.x, t = threadIdx.x;
  if (bx < 512) {
    body_wgemm(bx, t, ws);
  } else if (bx < 768) {
    body_zred(bx - 512, t, ws);
  } else {
    body_norm2(t, ws);
  }
}

// K7: compact U[u][3][64][64] (c: x, yr, yi; swizzle baked), LDS-staged stores.
// grid (125 ug, 16 by), block 256 = 4 b x 64 i, 16 u per block.
// R1: prefetch x16, Z loads behind, drain x->LDS, unrolled y loop.
// R5: pin the 16 prefetched x values live in VGPRs via empty asm.
__global__ void __launch_bounds__(256, 4)
k_u(const float* __restrict__ x, const float* __restrict__ ne_re,
    const float* __restrict__ ne_im, float* __restrict__ ws) {
  int ug = blockIdx.x, by = blockIdx.y;
  int t = threadIdx.x, q = t >> 6, i = t & 63;
  int b = by*4 + q;
  float invn = ws[WS_INV_DW];

  // (1) prefetch all 16 x values: independent coalesced 4B loads
  float xv[16];
  {
    const float* xp = x + ((size_t)b*VV + (size_t)ug*16)*CI + i;
    #pragma unroll
    for (int ul = 0; ul < 16; ++ul) xv[ul] = xp[(size_t)ul*CI];
    #pragma unroll
    for (int ul = 0; ul < 16; ++ul) asm volatile("" : "+v"(xv[ul]));
  }

  // (2) Z loads (16 x 8B, cache-resident) — land while x is in flight
  const float* Z = ws + WS_Z_DW;
  float zr[DD], zi[DD];
  #pragma unroll
  for (int d = 0; d < DD; ++d) {
    const float* zp = Z + (size_t)(d*4096 + b*64 + i) * 2;
    zr[d] = zp[0]; zi[d] = zp[1];
  }

  __shared__ uint16_t sStage[192 * 64];       // rr = ul*12 + c*4 + q
  int bkey = b & 7;
  int pos = (((i >> 3) ^ bkey) & 7)*8 + (i & 7);

  // (3) drain x -> LDS (frees xv registers before the FMA-heavy loop)
  #pragma unroll
  for (int ul = 0; ul < 16; ++ul)
    sStage[(ul*12 + 0 + q)*64 + pos] = (uint16_t)f2bf(xv[ul]);

  // (4) y compute, fully unrolled, split accumulators
  #pragma unroll
  for (int ul = 0; ul < 16; ++ul) {
    int u = ug*16 + ul;
    float yra = 0.f, yrb = 0.f, yia = 0.f, yib = 0.f;
    #pragma unroll
    for (int d = 0; d < DD; ++d) {
      float nr = ne_re[u*DD + d], ni = ne_im[u*DD + d];
      yra += nr*zr[d]; yrb += ni*zi[d];
      yia += nr*zi[d]; yib += ni*zr[d];
    }
    float yr = yra - yrb, yi = yia + yib;
    sStage[(ul*12 + 4 + q)*64 + pos] = (uint16_t)f2bf(yr * invn);
    sStage[(ul*12 + 8 + q)*64 + pos] = (uint16_t)f2bf(yi * invn);
  }
  __syncthreads();
  // flush: 192 rows x 128B, 32 rows per pass (8 lanes/row), 6 passes
  uint16_t* U = (uint16_t*)((char*)ws + WS_U_B);
  const uint4* sv = (const uint4*)sStage;
  #pragma unroll
  for (int pass = 0; pass < 6; ++pass) {
    int rr = pass*32 + (t >> 3), l8 = t & 7;
    int ul = rr / 12, rem = rr - ul*12;
    int c = rem >> 2, qq = rem & 3;
    uint4 v = sv[rr*8 + l8];
    *(uint4*)(U + (size_t)(ug*16 + ul)*12288 + c*4096 + (by*4 + qq)*64 + l8*8) = v;
  }
}

// K8: per-node MFMA from compact W,U. LDS pitch 80 elems (160B) -> <=2-way
// bank conflicts. Out stores: wave columns = (8 o)x(re,im) interleaved ->
// 16 consecutive dwords = 64B lines.
#define LP 80           // LDS row pitch (elems)
#define CSTRIDE 5120    // 64*LP: comp stride (elems)
__global__ void __launch_bounds__(512, 2)
k_final(const float* __restrict__ ws, float* __restrict__ out) {
  int u = blockIdx.x, t = threadIdx.x;
  __shared__ __align__(16) uint16_t sW[4 * CSTRIDE];   // 40960B
  __shared__ __align__(16) uint16_t sU[3 * CSTRIDE];   // 30720B
  const uint4* Wg = (const uint4*)((const char*)ws + WS_W_B + (size_t)u*32768);
  const uint4* Ug = (const uint4*)((const char*)ws + WS_U_B + (size_t)u*24576);
  #pragma unroll
  for (int j = 0; j < 4; ++j) {
    int idx = j*512 + t;                       // 2048 chunks of 16B
    int row = idx >> 3, col = idx & 7;
    *(uint4*)&sW[row*LP + col*8] = Wg[idx];
  }
  #pragma unroll
  for (int j = 0; j < 3; ++j) {
    int idx = j*512 + t;                       // 1536 chunks
    int row = idx >> 3, col = idx & 7;
    *(uint4*)&sU[row*LP + col*8] = Ug[idx];
  }
  __syncthreads();

  int w = t >> 6, lane = t & 63;
  int n16 = lane & 15, quad = lane >> 4;
  int o = w*8 + (n16 >> 1), half = n16 & 1;
  int okey = o & 7;
  uint32_t sgnmask = half ? 0u : 0x80008000u;  // negate Bi for re-half at cb=2
  f32x4 acc[4];
  #pragma unroll
  for (int m = 0; m < 4; ++m) acc[m] = (f32x4){0.f,0.f,0.f,0.f};

  #pragma unroll
  for (int ks = 0; ks < 6; ++ks) {
    int cb = ks >> 1;                          // 0,0,1,1,2,2
    int i8 = (ks & 1)*4 + quad;                // logical granule & 7
    int c  = (cb == 0) ? half : ((cb == 1) ? 2 + half : 3 - half);
    int slot = (i8 ^ okey) & 7;
    short8 bfrag = *(const short8*)&sW[c*CSTRIDE + o*LP + slot*8];
    if (cb == 2) {
      uint32_t* bu = (uint32_t*)&bfrag;
      #pragma unroll
      for (int jj = 0; jj < 4; ++jj) bu[jj] ^= sgnmask;
    }
    #pragma unroll
    for (int m = 0; m < 4; ++m) {
      int b = m*16 + n16;
      int aslot = (i8 ^ (b & 7)) & 7;
      short8 afrag = *(const short8*)&sU[cb*CSTRIDE + b*LP + aslot*8];
      acc[m] = __builtin_amdgcn_mfma_f32_16x16x32_bf16(afrag, bfrag, acc[m], 0, 0, 0);
    }
  }

  float bias = ws[WS_BIAS_DW + u*128 + w*16 + n16];
  #pragma unroll
  for (int m = 0; m < 4; ++m) {
    #pragma unroll
    for (int r = 0; r < 4; ++r) {
      int b = m*16 + quad*4 + r;
      out[((size_t)b*VV + u)*128 + w*16 + n16] = acc[m][r] + bias;
    }
  }
}

// ---------------------------------------------------------------------------
extern "C" void kernel_launch(void* const* d_in, const int* in_sizes, int n_in,
                              void* d_out, int out_size, void* d_ws, size_t ws_size,
                              hipStream_t stream) {
  (void)in_sizes; (void)n_in; (void)out_size; (void)ws_size;
  const float* x     = (const float*)d_in[0];
  const float* ne_re = (const float*)d_in[1];
  const float* ne_im = (const float*)d_in[2];
  const float* w_re  = (const float*)d_in[3];
  const float* w_im  = (const float*)d_in[4];
  const float* b_re  = (const float*)d_in[5];
  const float* b_im  = (const float*)d_in[6];
  float* out = (float*)d_out;
  float* ws  = (float*)d_ws;

  k_front<<<dim3(2892),    dim3(256), 0, stream>>>(x, ne_re, ne_im, w_re, w_im,
                                                   b_re, b_im, ws);
  k_mid  <<<dim3(769),     dim3(256), 0, stream>>>(ws);
  k_u    <<<dim3(125, 16), dim3(256), 0, stream>>>(x, ne_re, ne_im, ws);
  k_final<<<dim3(VV),      dim3(512), 0, stream>>>(ws, out);
}

// Round 15
// 179.940 us; speedup vs baseline: 1.3431x; 1.0089x over previous
//
#include <hip/hip_runtime.h>
#include <stdint.h>

// Problem constants
#define BB 64
#define VV 2000
#define DD 16
#define CI 64
#define CO 64

// ---- ws layout ----
// dword offsets (fp32 region)
#define WS_INV_DW   0
#define WS_Z_DW     1024                    // float2[16][4096]
#define WS_BIAS_DW  132096                  // fp32 [2000][128]  (idx = 2*o+half)
// byte offsets (bf16 regions), all 16B-aligned
#define WS_NE_B     1552384UL               // bf16 [2048][64]  (hi/lo split ne)
#define WS_RHS_B    1814528UL               // bf16 [16384][64] compact RHS
#define WS_U_B      4960256UL               // bf16 [2000][3][64][64] compact U
#define WS_W_B      54112256UL              // bf16 [2000][4][64][64] compact W
// R8: ZP (z partials) and NP (norm1 partials) moved to DEDICATED space at
// 128 MiB (ws is 268 MB; we use ~143 MB total). The old U-region aliasing
// would collide with k_front's new direct U[c=0] writes.
#define WS_ZP_DW    33554432                // byte 128 MiB; 8.4 MB
#define WS_NP_DW    (WS_ZP_DW + 2097152)    // 100 blocks x 512 floats

typedef __attribute__((ext_vector_type(8))) short short8;
typedef __attribute__((ext_vector_type(4))) float f32x4;

__device__ __forceinline__ uint32_t f2bf(float f) {
  uint32_t u = __float_as_uint(f);
  return (u + 0x7FFFu + ((u >> 16) & 1u)) >> 16;   // RNE
}

// Direct global->LDS DMA, 16B per lane. LDS dest = wave-uniform base +
// lane*16; global src is per-lane. No VGPR round trip, no scratch.
__device__ __forceinline__ void gload_lds16(const void* g, void* l) {
  __builtin_amdgcn_global_load_lds(
      (const __attribute__((address_space(1))) uint32_t*)g,
      (__attribute__((address_space(3))) uint32_t*)l, 16, 0, 0);
}

// ---------------------------------------------------------------------------
// Component bodies, fused into k_front / k_mid by blockIdx range.
//   k_front: {z (+U[c=0] write), rhs, norm1, bias, ne}   (independent)
//   k_mid:   {wgemm, zred, norm2}        (all need only k_front)
//   k_u:     needs Z + INV (k_mid); writes U[c=1,2] only
//   k_final: needs W (k_mid) + U (k_front c=0, k_u c=1,2) + bias (k_front)
// R8: body_z emits bf16(x) directly into U[c=0] (it already holds x in LDS),
// so k_u no longer reads x from HBM (-21 MB fetch) nor stores the x third
// of U (-16 MB of its writes). Same swizzle (pos keyed by b&7) as k_u used.
// ---------------------------------------------------------------------------

// z: Z partials. 1024 virtual blocks = (b:64)x(chunk:16).
// R2: wave-uniform v-range (scalar ne loads), x tile staged in LDS.
// R5: staging via global_load_lds (reg-staging lived in scratch).
// R8: per-iteration 2B/lane store of bf16(xv) -> U[c=0] (coalesces to one
// 128B wave-store per row, fire-and-forget under the FMA chain).
__device__ __forceinline__ void body_z(int bz, int t,
    const float* __restrict__ x, const float* __restrict__ ne_re,
    const float* __restrict__ ne_im, float* __restrict__ ws) {
  int b = bz >> 4, c = bz & 15;
  int lane = t & 63;
  int w = __builtin_amdgcn_readfirstlane(t >> 6);   // wave-uniform in SGPR
  __shared__ __align__(16) float smem[8192];        // 32 KB: x-tile, then sred

  int vbase = c * 125;

  // stage x[b, vbase..vbase+125, :] = 32000 B contiguous into LDS via DMA.
  {
    const float4* xg = (const float4*)(x + ((size_t)b * VV + vbase) * CI);
    int wb = t & 192;                               // w*64, uniform per wave
    #pragma unroll
    for (int p = 0; p < 8; ++p) {
      int idx = p * 256 + t;
      if (idx < 2000)
        gload_lds16(xg + idx, &smem[(p * 256 + wb) * 4]);
    }
  }
  __syncthreads();                                  // compiler drains vmcnt

  float zr[DD], zi[DD];
  #pragma unroll
  for (int d = 0; d < DD; ++d) { zr[d] = 0.f; zi[d] = 0.f; }

  uint16_t* Ux = (uint16_t*)((char*)ws + WS_U_B);
  int bkey = b & 7;
  int pos = (((lane >> 3) ^ bkey) & 7)*8 + (lane & 7);

  int lv0 = (w * 125) >> 2;                         // uniform bounds (SGPR)
  int lv1 = ((w + 1) * 125) >> 2;
  #pragma unroll 4
  for (int lv = lv0; lv < lv1; ++lv) {
    float xv = smem[lv * 64 + lane];                // stride-1: conflict-free
    int v = vbase + lv;                             // uniform -> s_load ne
    Ux[(size_t)v*12288 + b*64 + pos] = (uint16_t)f2bf(xv);  // U[c=0]
    #pragma unroll
    for (int d = 0; d < DD; ++d) {
      zr[d] += ne_re[v*DD + d] * xv;
      zi[d] -= ne_im[v*DD + d] * xv;
    }
  }
  __syncthreads();                                  // all waves done with x-tile

  #pragma unroll
  for (int d = 0; d < DD; ++d) {
    smem[w*2048 + d*128 + lane*2 + 0] = zr[d];
    smem[w*2048 + d*128 + lane*2 + 1] = zi[d];
  }
  __syncthreads();
  float* ZP = ws + WS_ZP_DW;
  #pragma unroll
  for (int k = 0; k < 8; ++k) {
    int j = t + k*256;
    float s = smem[j] + smem[2048 + j] + smem[4096 + j] + smem[6144 + j];
    int d = j >> 7, r = j & 127;
    ZP[(size_t)c*131072 + d*8192 + b*128 + r] = s;
  }
}

// ne: NE[u][col] bf16, col = h*32 + d*2 + p; h=0: bf16(ne), h=1: bf16(ne - hi)
__device__ __forceinline__ void body_ne(int bx, int t,
    const float* __restrict__ ne_re, const float* __restrict__ ne_im,
    float* __restrict__ ws) {
  int gid = bx * 256 + t;                     // 512 blocks -> 131072
  int u = gid >> 6, col = gid & 63;
  int h = col >> 5, kk = col & 31, d = kk >> 1, p = kk & 1;
  float v = 0.f;
  if (u < VV) v = p ? ne_im[u*DD + d] : ne_re[u*DD + d];
  uint32_t hi = f2bf(v);
  uint32_t ov = h ? f2bf(v - __uint_as_float(hi << 16)) : hi;
  ((uint16_t*)((char*)ws + WS_NE_B))[gid] = (uint16_t)ov;
}

// rhs: compact RHS[n'][k]. R7: 256 blocks = (c:4)x(ig4:16)x(dq:4); each block
// handles d = dq*4..dq*4+3 and writes its own disjoint uint4 pair.
__device__ __forceinline__ void body_rhs(int bx, int t,
    const float* __restrict__ w_re, const float* __restrict__ w_im,
    float* __restrict__ ws) {
  int c = bx >> 6, sub = bx & 63;
  int ig4 = sub & 15, dq = sub >> 4;
  int o = t & 63, il = t >> 6;
  int i = ig4*4 + il;
  int cb = c >> 1;                     // 0: wA = w0-w2, 1: wB = w1+2w2
  int imf = c & 1;                     // odd comp: (Im, Re); even: (Re, -Im)

  uint32_t row32[4];
  #pragma unroll
  for (int d4 = 0; d4 < 4; ++d4) {
    int d = dq*4 + d4;
    int b0 = (d*192 + i)*64 + o;       // w[d,kc,i,o]: d stride 12288, kc 4096
    float vre, vim;
    if (cb == 0) {
      vre = w_re[b0] - w_re[b0 + 8192];
      vim = w_im[b0] - w_im[b0 + 8192];
    } else {
      vre = w_re[b0 + 4096] + 2.f*w_re[b0 + 8192];
      vim = w_im[b0 + 4096] + 2.f*w_im[b0 + 8192];
    }
    float q0 = imf ? vim : vre;
    float q1 = imf ? vre : -vim;
    row32[d4] = f2bf(q0) | (f2bf(q1) << 16);
  }
  int s = ((i >> 3) ^ (o & 7)) & 7;
  int n = c*4096 + o*64 + s*8 + (i & 7);
  uint4* dst = (uint4*)((uint16_t*)((char*)ws + WS_RHS_B) + (size_t)n*64);
  uint4 qv = make_uint4(row32[0], row32[1], row32[2], row32[3]);
  dst[dq]     = qv;   // h=0
  dst[dq + 4] = qv;   // h=1 duplicate (hi/lo ne split reconstructs fp32)
}

// norm1: partial Gram. R7: 100 virtual blocks x 20 v. Partials to NP.
__device__ __forceinline__ void body_norm1(int bx, int t,
    const float* __restrict__ ne_re, const float* __restrict__ ne_im,
    float* __restrict__ ws) {
  int d = t >> 4, e = t & 15;
  int v0 = bx * 20;
  float gr = 0.f, gi = 0.f;
  #pragma unroll 4
  for (int v = v0; v < v0 + 20; ++v) {
    float ar = ne_re[v*DD + d], ai = ne_im[v*DD + d];
    float br = ne_re[v*DD + e], bi = ne_im[v*DD + e];
    gr += ar*br + ai*bi;
    gi += ar*bi - ai*br;
  }
  float* NP = ws + WS_NP_DW;
  NP[bx*512 + 2*t]     = gr;
  NP[bx*512 + 2*t + 1] = gi;
}

// bias: bias2[u][2*o+half] fp32 (interleaved so k_final stores are linear)
__device__ __forceinline__ void body_bias(int bx, int t,
    const float* __restrict__ ne_re, const float* __restrict__ ne_im,
    const float* __restrict__ b_re, const float* __restrict__ b_im,
    float* __restrict__ ws) {
  int gid = bx * 256 + t;                     // 1000 blocks -> 256000
  int u = gid >> 7, idx = gid & 127;
  int o = idx >> 1, half = idx & 1;
  float acc = 0.f;
  #pragma unroll
  for (int d = 0; d < DD; ++d) {
    float nr = ne_re[u*DD + d], ni = ne_im[u*DD + d];
    float pr = b_re[d*CO + o],  pi = b_im[d*CO + o];
    acc += half ? (nr*pi + ni*pr) : (nr*pr - ni*pi);
  }
  ws[WS_BIAS_DW + gid] = acc;
}

// wgemm: W GEMM -> compact Wc[u][16384].
__device__ __forceinline__ void body_wgemm(int bx, int t, float* __restrict__ ws) {
  const uint16_t* NE  = (const uint16_t*)((char*)ws + WS_NE_B);
  const uint16_t* RHS = (const uint16_t*)((char*)ws + WS_RHS_B);
  uint32_t*       W   = (uint32_t*)((char*)ws + WS_W_B);
  int ut = bx & 31, nc = bx >> 5;
  int w = t >> 6, lane = t & 63;
  int n16 = lane & 15, quad = lane >> 4;
  short8 a[4][2];
  #pragma unroll
  for (int m = 0; m < 4; ++m) {
    int u = ut*64 + m*16 + n16;
    a[m][0] = *(const short8*)(NE + u*64 + quad*8);
    a[m][1] = *(const short8*)(NE + u*64 + 32 + quad*8);
  }
  int nbase = nc*1024 + w*256;
  #pragma unroll 2
  for (int pt = 0; pt < 8; ++pt) {
    int nb = nbase + pt*32;
    const uint16_t* r0 = RHS + (size_t)(nb + 2*n16 + 0)*64 + quad*8;
    const uint16_t* r1 = RHS + (size_t)(nb + 2*n16 + 1)*64 + quad*8;
    short8 b00 = *(const short8*)r0;
    short8 b01 = *(const short8*)(r0 + 32);
    short8 b10 = *(const short8*)r1;
    short8 b11 = *(const short8*)(r1 + 32);
    #pragma unroll
    for (int m = 0; m < 4; ++m) {
      f32x4 acc0 = (f32x4){0.f,0.f,0.f,0.f};
      f32x4 acc1 = (f32x4){0.f,0.f,0.f,0.f};
      acc0 = __builtin_amdgcn_mfma_f32_16x16x32_bf16(a[m][0], b00, acc0, 0, 0, 0);
      acc0 = __builtin_amdgcn_mfma_f32_16x16x32_bf16(a[m][1], b01, acc0, 0, 0, 0);
      acc1 = __builtin_amdgcn_mfma_f32_16x16x32_bf16(a[m][0], b10, acc1, 0, 0, 0);
      acc1 = __builtin_amdgcn_mfma_f32_16x16x32_bf16(a[m][1], b11, acc1, 0, 0, 0);
      #pragma unroll
      for (int r = 0; r < 4; ++r) {
        int u = ut*64 + m*16 + quad*4 + r;
        if (u < VV) {
          uint32_t pk = f2bf(acc0[r]) | (f2bf(acc1[r]) << 16);
          W[(size_t)u*8192 + (nb >> 1) + n16] = pk;
        }
      }
    }
  }
}

// zred: Z = sum over 16 chunks of ZP. 256 virtual blocks.
__device__ __forceinline__ void body_zred(int bx, int t, float* __restrict__ ws) {
  int g = bx * 256 + t;
  const float2* ZP2 = (const float2*)(ws + WS_ZP_DW);
  float2 acc = make_float2(0.f, 0.f);
  #pragma unroll
  for (int c = 0; c < 16; ++c) {
    float2 v = ZP2[(size_t)c*65536 + g];
    acc.x += v.x; acc.y += v.y;
  }
  ((float2*)(ws + WS_Z_DW))[g] = acc;
}

// norm2: reduce NP partials -> INV. 1 virtual block. 100 partials.
__device__ __forceinline__ void body_norm2(int t, float* __restrict__ ws) {
  const float* NP = ws + WS_NP_DW;
  float gr = 0.f, gi = 0.f;
  #pragma unroll
  for (int p = 0; p < 100; ++p) {
    gr += NP[p*512 + 2*t];
    gi += NP[p*512 + 2*t + 1];
  }
  __shared__ float red[256];
  red[t] = gr*gr + gi*gi;
  __syncthreads();
  for (int k = 128; k > 0; k >>= 1) {
    if (t < k) red[t] += red[t + k];
    __syncthreads();
  }
  if (t == 0) ws[WS_INV_DW] = 1.0f / sqrtf(red[0]);
}

// ---------------------------------------------------------------------------
// Fused dispatchers
// ---------------------------------------------------------------------------

// k_front: 2892 blocks, longest-per-block first:
//   z [0,1024) | rhs [1024,1280) | norm1 [1280,1380) |
//   bias [1380,2380) | ne [2380,2892)
__global__ void __launch_bounds__(256, 4)
k_front(const float* __restrict__ x, const float* __restrict__ ne_re,
        const float* __restrict__ ne_im, const float* __restrict__ w_re,
        const float* __restrict__ w_im, const float* __restrict__ b_re,
        const float* __restrict__ b_im, float* __restrict__ ws) {
  int bx = blockIdx.x, t = threadIdx.x;
  if (bx < 1024) {
    body_z(bx, t, x, ne_re, ne_im, ws);
  } else if (bx < 1280) {
    body_rhs(bx - 1024, t, w_re, w_im, ws);
  } else if (bx < 1380) {
    body_norm1(bx - 1280, t, ne_re, ne_im, ws);
  } else if (bx < 2380) {
    body_bias(bx - 1380, t, ne_re, ne_im, b_re, b_im, ws);
  } else {
    body_ne(bx - 2380, t, ne_re, ne_im, ws);
  }
}

// k_mid: 769 blocks. wgemm [0,512) | zred [512,768) | norm2 768.
// ZP/NP now dedicated (no aliasing) -> no ordering constraints here.
__global__ void __launch_bounds__(256, 4)
k_mid(float* __restrict__ ws) {
  int bx = blockIdx.x, t = threadIdx.x;
  if (bx < 512) {
    body_wgemm(bx, t, ws);
  } else if (bx < 768) {
    body_zred(bx - 512, t, ws);
  } else {
    body_norm2(t, ws);
  }
}

// K7: y-only now. compact U[u][1,2][64][64] (yr, yi; swizzle baked).
// grid (125 ug, 16 by), block 256 = 4 b x 64 i, 16 u per block.
// R8: x path removed entirely (k_front writes U[c=0]); sStage 128 rows.
__global__ void __launch_bounds__(256, 4)
k_u(const float* __restrict__ x, const float* __restrict__ ne_re,
    const float* __restrict__ ne_im, float* __restrict__ ws) {
  (void)x;
  int ug = blockIdx.x, by = blockIdx.y;
  int t = threadIdx.x, q = t >> 6, i = t & 63;
  int b = by*4 + q;
  float invn = ws[WS_INV_DW];

  // Z loads (16 x 8B, cache-resident)
  const float* Z = ws + WS_Z_DW;
  float zr[DD], zi[DD];
  #pragma unroll
  for (int d = 0; d < DD; ++d) {
    const float* zp = Z + (size_t)(d*4096 + b*64 + i) * 2;
    zr[d] = zp[0]; zi[d] = zp[1];
  }

  __shared__ uint16_t sStage[128 * 64];       // rr = ul*8 + cc*4 + q
  int bkey = b & 7;
  int pos = (((i >> 3) ^ bkey) & 7)*8 + (i & 7);

  // y compute, fully unrolled, split accumulators
  #pragma unroll
  for (int ul = 0; ul < 16; ++ul) {
    int u = ug*16 + ul;
    float yra = 0.f, yrb = 0.f, yia = 0.f, yib = 0.f;
    #pragma unroll
    for (int d = 0; d < DD; ++d) {
      float nr = ne_re[u*DD + d], ni = ne_im[u*DD + d];
      yra += nr*zr[d]; yrb += ni*zi[d];
      yia += nr*zi[d]; yib += ni*zr[d];
    }
    float yr = yra - yrb, yi = yia + yib;
    sStage[(ul*8 + 0 + q)*64 + pos] = (uint16_t)f2bf(yr * invn);
    sStage[(ul*8 + 4 + q)*64 + pos] = (uint16_t)f2bf(yi * invn);
  }
  __syncthreads();
  // flush: 128 rows x 128B, 32 rows per pass (8 lanes/row), 4 passes
  uint16_t* U = (uint16_t*)((char*)ws + WS_U_B);
  const uint4* sv = (const uint4*)sStage;
  #pragma unroll
  for (int pass = 0; pass < 4; ++pass) {
    int rr = pass*32 + (t >> 3), l8 = t & 7;
    int ul = rr >> 3, rem = rr & 7;
    int cc = rem >> 2, qq = rem & 3;             // cc: 0=yr->c=1, 1=yi->c=2
    uint4 v = sv[rr*8 + l8];
    *(uint4*)(U + (size_t)(ug*16 + ul)*12288 + (1+cc)*4096 + (by*4 + qq)*64 + l8*8) = v;
  }
}

// K8: per-node MFMA from compact W,U. LDS pitch 80 elems (160B) -> <=2-way
// bank conflicts. Out stores: wave columns = (8 o)x(re,im) interleaved ->
// 16 consecutive dwords = 64B lines.
#define LP 80           // LDS row pitch (elems)
#define CSTRIDE 5120    // 64*LP: comp stride (elems)
__global__ void __launch_bounds__(512, 2)
k_final(const float* __restrict__ ws, float* __restrict__ out) {
  int u = blockIdx.x, t = threadIdx.x;
  __shared__ __align__(16) uint16_t sW[4 * CSTRIDE];   // 40960B
  __shared__ __align__(16) uint16_t sU[3 * CSTRIDE];   // 30720B
  const uint4* Wg = (const uint4*)((const char*)ws + WS_W_B + (size_t)u*32768);
  const uint4* Ug = (const uint4*)((const char*)ws + WS_U_B + (size_t)u*24576);
  #pragma unroll
  for (int j = 0; j < 4; ++j) {
    int idx = j*512 + t;                       // 2048 chunks of 16B
    int row = idx >> 3, col = idx & 7;
    *(uint4*)&sW[row*LP + col*8] = Wg[idx];
  }
  #pragma unroll
  for (int j = 0; j < 3; ++j) {
    int idx = j*512 + t;                       // 1536 chunks
    int row = idx >> 3, col = idx & 7;
    *(uint4*)&sU[row*LP + col*8] = Ug[idx];
  }
  __syncthreads();

  int w = t >> 6, lane = t & 63;
  int n16 = lane & 15, quad = lane >> 4;
  int o = w*8 + (n16 >> 1), half = n16 & 1;
  int okey = o & 7;
  uint32_t sgnmask = half ? 0u : 0x80008000u;  // negate Bi for re-half at cb=2
  f32x4 acc[4];
  #pragma unroll
  for (int m = 0; m < 4; ++m) acc[m] = (f32x4){0.f,0.f,0.f,0.f};

  #pragma unroll
  for (int ks = 0; ks < 6; ++ks) {
    int cb = ks >> 1;                          // 0,0,1,1,2,2
    int i8 = (ks & 1)*4 + quad;                // logical granule & 7
    int c  = (cb == 0) ? half : ((cb == 1) ? 2 + half : 3 - half);
    int slot = (i8 ^ okey) & 7;
    short8 bfrag = *(const short8*)&sW[c*CSTRIDE + o*LP + slot*8];
    if (cb == 2) {
      uint32_t* bu = (uint32_t*)&bfrag;
      #pragma unroll
      for (int jj = 0; jj < 4; ++jj) bu[jj] ^= sgnmask;
    }
    #pragma unroll
    for (int m = 0; m < 4; ++m) {
      int b = m*16 + n16;
      int aslot = (i8 ^ (b & 7)) & 7;
      short8 afrag = *(const short8*)&sU[cb*CSTRIDE + b*LP + aslot*8];
      acc[m] = __builtin_amdgcn_mfma_f32_16x16x32_bf16(afrag, bfrag, acc[m], 0, 0, 0);
    }
  }

  float bias = ws[WS_BIAS_DW + u*128 + w*16 + n16];
  #pragma unroll
  for (int m = 0; m < 4; ++m) {
    #pragma unroll
    for (int r = 0; r < 4; ++r) {
      int b = m*16 + quad*4 + r;
      out[((size_t)b*VV + u)*128 + w*16 + n16] = acc[m][r] + bias;
    }
  }
}

// ---------------------------------------------------------------------------
extern "C" void kernel_launch(void* const* d_in, const int* in_sizes, int n_in,
                              void* d_out, int out_size, void* d_ws, size_t ws_size,
                              hipStream_t stream) {
  (void)in_sizes; (void)n_in; (void)out_size; (void)ws_size;
  const float* x     = (const float*)d_in[0];
  const float* ne_re = (const float*)d_in[1];
  const float* ne_im = (const float*)d_in[2];
  const float* w_re  = (const float*)d_in[3];
  const float* w_im  = (const float*)d_in[4];
  const float* b_re  = (const float*)d_in[5];
  const float* b_im  = (const float*)d_in[6];
  float* out = (float*)d_out;
  float* ws  = (float*)d_ws;

  k_front<<<dim3(2892),    dim3(256), 0, stream>>>(x, ne_re, ne_im, w_re, w_im,
                                                   b_re, b_im, ws);
  k_mid  <<<dim3(769),     dim3(256), 0, stream>>>(ws);
  k_u    <<<dim3(125, 16), dim3(256), 0, stream>>>(x, ne_re, ne_im, ws);
  k_final<<<dim3(VV),      dim3(512), 0, stream>>>(ws, out);
}